// Round 5
// baseline (3604.129 us; speedup 1.0000x reference)
//
#include <hip/hip_runtime.h>
#include <hip/hip_bf16.h>

#define BB 8
#define NN 1024
#define DD 128
#define HH 4
#define LL 4

typedef __attribute__((ext_vector_type(8))) short bf16x8;
typedef __attribute__((ext_vector_type(4))) float f32x4;
typedef __attribute__((ext_vector_type(8))) unsigned short u16x8;

__device__ __forceinline__ unsigned short f2bf(float f) {
  union { float f; unsigned int u; } v; v.f = f;
  unsigned int u = v.u;
  return (unsigned short)((u + 0x7FFFu + ((u >> 16) & 1u)) >> 16);
}
__device__ __forceinline__ float bf2f(unsigned short s) {
  union { unsigned int u; float f; } v; v.u = ((unsigned int)s) << 16;
  return v.f;
}
__device__ __forceinline__ unsigned short f2h(float f) {
  union { _Float16 h; unsigned short u; } v; v.h = (_Float16)f;
  return v.u;
}
__device__ __forceinline__ float h2f(unsigned short u) {
  union { unsigned short u; _Float16 h; } v; v.u = u;
  return (float)v.h;
}

// ---------------- adj transpose to bf16: out[b][r][p] = bf16(in[b][p][r]) -----
__global__ __launch_bounds__(256) void k_transpose_bf16(const float* __restrict__ in,
                                                        unsigned short* __restrict__ out) {
  __shared__ float t[32][33];
  int b = blockIdx.z;
  int x0 = blockIdx.x * 32, y0 = blockIdx.y * 32;
  int tx = threadIdx.x & 31, ty = threadIdx.x >> 5; // 32 x 8
  const float* ib = in + (size_t)b * NN * NN;
  unsigned short* ob = out + (size_t)b * NN * NN;
#pragma unroll
  for (int j = 0; j < 32; j += 8)
    t[ty + j][tx] = ib[(size_t)(y0 + ty + j) * NN + x0 + tx];
  __syncthreads();
#pragma unroll
  for (int j = 0; j < 32; j += 8)
    ob[(size_t)(x0 + ty + j) * NN + y0 + tx] = f2bf(t[tx][ty + j]);
}

// ---------------- fp32 -> bf16 copy (adj normal-orientation) -------------------
__global__ __launch_bounds__(256) void k_copy_bf16(const float* __restrict__ in,
                                                   unsigned short* __restrict__ out) {
  int idx = blockIdx.x * 256 + threadIdx.x; // 4 floats per thread
  float4 v = ((const float4*)in)[idx];
  uint2 pv;
  pv.x = (unsigned int)f2bf(v.x) | ((unsigned int)f2bf(v.y) << 16);
  pv.y = (unsigned int)f2bf(v.z) | ((unsigned int)f2bf(v.w) << 16);
  ((uint2*)out)[idx] = pv;
}

// ------- weight transpose: in [nm][128][Nn] fp32 -> out [nm][Nn][128] bf16 -----
__global__ __launch_bounds__(256) void k_wtrans(const float* __restrict__ in,
                                                unsigned short* __restrict__ out, int Nn) {
  __shared__ float t[32][33];
  int m = blockIdx.z;
  const float* ib = in + (size_t)m * 128 * Nn;
  unsigned short* ob = out + (size_t)m * Nn * 128;
  int k0 = blockIdx.x * 32, n0 = blockIdx.y * 32;
  int tx = threadIdx.x & 31, ty = threadIdx.x >> 5;
#pragma unroll
  for (int j = 0; j < 32; j += 8)
    t[ty + j][tx] = ib[(size_t)(k0 + ty + j) * Nn + n0 + tx];
  __syncthreads();
#pragma unroll
  for (int j = 0; j < 32; j += 8)
    ob[(size_t)(n0 + ty + j) * 128 + k0 + tx] = f2bf(t[tx][ty + j]);
}

// ------- SIMT K=128 GEMM (embed only): C = A[M,128] @ Bw[128,Nn]; fp32+bf16 ----
__global__ __launch_bounds__(256) void k_gemm_k128(const float* __restrict__ A,
                                                   const float* __restrict__ Bw,
                                                   float* __restrict__ C,
                                                   unsigned short* __restrict__ Cbf,
                                                   int M, int Nn) {
  __shared__ __align__(16) float As[32][68];
  __shared__ __align__(16) float Bs[32][68];
  const int tm = blockIdx.x * 64, tn = blockIdx.y * 64;
  const int tid = threadIdx.x;
  const int ty = tid >> 4, tx = tid & 15;
  float acc[4][4] = {};
  for (int kc = 0; kc < 128; kc += 32) {
#pragma unroll
    for (int e = 0; e < 8; ++e) {
      int fl = tid + e * 256;
      int r = fl >> 5, k = fl & 31;
      As[k][r] = A[(size_t)(tm + r) * 128 + kc + k];
    }
#pragma unroll
    for (int e = 0; e < 8; ++e) {
      int fl = tid + e * 256;
      int k = fl >> 6, n = fl & 63;
      Bs[k][n] = Bw[(size_t)(kc + k) * Nn + tn + n];
    }
    __syncthreads();
#pragma unroll
    for (int kk = 0; kk < 32; ++kk) {
      float a4[4], b4[4];
      *(float4*)a4 = *(const float4*)&As[kk][ty * 4];
      *(float4*)b4 = *(const float4*)&Bs[kk][tx * 4];
#pragma unroll
      for (int i = 0; i < 4; ++i)
#pragma unroll
        for (int j = 0; j < 4; ++j) acc[i][j] += a4[i] * b4[j];
    }
    __syncthreads();
  }
#pragma unroll
  for (int i = 0; i < 4; ++i) {
    size_t base = (size_t)(tm + ty * 4 + i) * Nn + tn + tx * 4;
    *(float4*)&C[base] = *(float4*)acc[i];
    uint2 pv;
    pv.x = (unsigned int)f2bf(acc[i][0]) | ((unsigned int)f2bf(acc[i][1]) << 16);
    pv.y = (unsigned int)f2bf(acc[i][2]) | ((unsigned int)f2bf(acc[i][3]) << 16);
    *(uint2*)&Cbf[base] = pv;
  }
}

// ------- MFMA NT GEMM, K=128: out[M,Nn](bf16) = A[M,128](bf16) @ Bt[Nn,128]^T --
// When hT != null (Nn==512 h-gemm): also write hT[b,i][q][node] transposed copy.
__global__ __launch_bounds__(256) void k_gemm_nt(const unsigned short* __restrict__ A,
                                                 const unsigned short* __restrict__ Bt,
                                                 const float* __restrict__ bias,
                                                 unsigned short* __restrict__ outp,
                                                 unsigned short* __restrict__ hT,
                                                 int Nn) {
  const int m0 = blockIdx.x * 64, n0 = blockIdx.y * 64;
  const int tid = threadIdx.x;
  const int wave = tid >> 6, lane = tid & 63;
  const int l15 = lane & 15, kq = lane >> 4;
  __shared__ __align__(16) unsigned short O[64][72];
  const unsigned short* aP = A + (size_t)(m0 + wave * 16 + l15) * 128;
  f32x4 acc[4] = {};
#pragma unroll
  for (int kk = 0; kk < 4; ++kk) {
    bf16x8 aF = *(const bf16x8*)(aP + (kk * 4 + kq) * 8);
#pragma unroll
    for (int cb = 0; cb < 4; ++cb) {
      bf16x8 bF = *(const bf16x8*)(Bt + (size_t)(n0 + cb * 16 + l15) * 128 + (kk * 4 + kq) * 8);
      acc[cb] = __builtin_amdgcn_mfma_f32_16x16x32_bf16(aF, bF, acc[cb], 0, 0, 0);
    }
  }
#pragma unroll
  for (int cb = 0; cb < 4; ++cb) {
    float bv = bias ? bias[n0 + cb * 16 + l15] : 0.f;
#pragma unroll
    for (int rg = 0; rg < 4; ++rg)
      O[wave * 16 + kq * 4 + rg][cb * 16 + l15] = f2bf(acc[cb][rg] + bv);
  }
  if (hT) { // transposed copy, direct from regs: 4 consecutive nodes per lane
    const int b = m0 >> 10;
    const int head = n0 >> 7, q0 = n0 & 127;
    unsigned short* hb2 = hT + (size_t)(b * HH + head) * 128 * NN;
#pragma unroll
    for (int cb = 0; cb < 4; ++cb) {
      float bv = bias ? bias[n0 + cb * 16 + l15] : 0.f;
      int q = q0 + cb * 16 + l15;
      uint2 pv;
      pv.x = (unsigned int)f2bf(acc[cb][0] + bv) | ((unsigned int)f2bf(acc[cb][1] + bv) << 16);
      pv.y = (unsigned int)f2bf(acc[cb][2] + bv) | ((unsigned int)f2bf(acc[cb][3] + bv) << 16);
      *(uint2*)(hb2 + (size_t)q * NN + (m0 & 1023) + wave * 16 + kq * 4) = pv;
    }
  }
  __syncthreads();
#pragma unroll
  for (int it = 0; it < 2; ++it) {
    int row = (tid >> 3) + it * 32, ch = tid & 7;
    *(uint4*)&outp[(size_t)(m0 + row) * Nn + n0 + ch * 8] = *(uint4*)&O[row][ch * 8];
  }
}

// ------- E tile via MFMA -> fp16 [p][r]: e = g[p]·h[r] + h[p]·g[r], symmetric --
// Both A and B fragments direct from global (k-minor layout == frag layout).
__global__ __launch_bounds__(256) void k_e2(const unsigned short* __restrict__ g,
                                            const unsigned short* __restrict__ h,
                                            unsigned short* __restrict__ e, int b0) {
  const int tp = blockIdx.x, tr = blockIdx.y;
  if (tp > tr) return; // symmetric: upper-triangular tile pairs only
  const int gi = blockIdx.z;
  const int b = b0 + (gi >> 2), i = gi & 3;
  const int p0 = tp * 64, r0 = tr * 64;
  const bool diag = (tp == tr);
  const int tid = threadIdx.x, w = tid >> 6, lane = tid & 63;
  const int l15 = lane & 15, kq = lane >> 4;
  const unsigned short* gb = g + (size_t)b * NN * 512 + i * 128;
  const unsigned short* hb = h + (size_t)b * NN * 512 + i * 128;
  const unsigned short* aG = gb + (size_t)(p0 + w * 16 + l15) * 512;
  const unsigned short* aH = hb + (size_t)(p0 + w * 16 + l15) * 512;
  f32x4 acc[4] = {};
#pragma unroll
  for (int kk = 0; kk < 4; ++kk) {
    const int ko = (kk * 4 + kq) * 8;
    bf16x8 gA = *(const bf16x8*)(aG + ko);
    bf16x8 hA = *(const bf16x8*)(aH + ko);
#pragma unroll
    for (int cb = 0; cb < 4; ++cb) {
      const size_t rr = (size_t)(r0 + cb * 16 + l15) * 512 + ko;
      bf16x8 gB = *(const bf16x8*)(gb + rr);
      bf16x8 hB = *(const bf16x8*)(hb + rr);
      acc[cb] = __builtin_amdgcn_mfma_f32_16x16x32_bf16(gA, hB, acc[cb], 0, 0, 0);
      acc[cb] = __builtin_amdgcn_mfma_f32_16x16x32_bf16(hA, gB, acc[cb], 0, 0, 0);
    }
  }
  __shared__ unsigned short eN[64 * 72], eT[64 * 72];
#pragma unroll
  for (int cb = 0; cb < 4; ++cb)
#pragma unroll
    for (int rg = 0; rg < 4; ++rg) {
      const int pl = w * 16 + kq * 4 + rg, rl = cb * 16 + l15;
      const unsigned short v = f2h(acc[cb][rg]);
      eN[pl * 72 + rl] = v;
      if (!diag) eT[rl * 72 + pl] = v;
    }
  __syncthreads();
  unsigned short* eb = e + (size_t)gi * NN * NN;
#pragma unroll
  for (int it = 0; it < 2; ++it) {
    const int row = (tid >> 3) + it * 32, ch = tid & 7;
    *(uint4*)&eb[(size_t)(p0 + row) * NN + r0 + ch * 8] = *(uint4*)&eN[row * 72 + ch * 8];
    if (!diag)
      *(uint4*)&eb[(size_t)(r0 + row) * NN + p0 + ch * 8] = *(uint4*)&eT[row * 72 + ch * 8];
  }
}

// ------- per-column softmax stats: mx[r], inv[r] (E column r == E row r) -------
__global__ __launch_bounds__(128) void k_stats(const unsigned short* __restrict__ e,
                                               const unsigned short* __restrict__ adjT,
                                               const float* __restrict__ adj,
                                               float2* __restrict__ stats, int b0) {
  const int col = blockIdx.x; // gi*N + r
  const int r = col & (NN - 1);
  const int gi = col >> 10;
  const int b = b0 + (gi >> 2);
  const unsigned short* erow = e + (size_t)col * NN;
  const int tid = threadIdx.x;
  u16x8 ev = *(const u16x8*)(erow + tid * 8);
  float s[8];
  if (adjT) {
    u16x8 av = *(const u16x8*)(adjT + ((size_t)b * NN + r) * NN + tid * 8);
#pragma unroll
    for (int j = 0; j < 8; ++j) s[j] = ((unsigned short)av[j]) ? h2f((unsigned short)ev[j]) : 0.f;
  } else {
    const float* acol = adj + (size_t)b * NN * NN + r;
#pragma unroll
    for (int j = 0; j < 8; ++j)
      s[j] = (acol[(size_t)(tid * 8 + j) * NN] > 0.f) ? h2f((unsigned short)ev[j]) : 0.f;
  }
  float mx = s[0];
#pragma unroll
  for (int j = 1; j < 8; ++j) mx = fmaxf(mx, s[j]);
#pragma unroll
  for (int o = 32; o; o >>= 1) mx = fmaxf(mx, __shfl_xor(mx, o));
  __shared__ float sm[2], ss[2];
  const int wv = tid >> 6, ln = tid & 63;
  if (ln == 0) sm[wv] = mx;
  __syncthreads();
  mx = fmaxf(sm[0], sm[1]);
  float ps = 0.f;
#pragma unroll
  for (int j = 0; j < 8; ++j) ps += __expf(s[j] - mx); // masked -> exp(0-mx)
#pragma unroll
  for (int o = 32; o; o >>= 1) ps += __shfl_xor(ps, o);
  if (ln == 0) ss[wv] = ps;
  __syncthreads();
  if (tid == 0) stats[col] = make_float2(mx, 1.f / (ss[0] + ss[1]));
}

// ------- att[p][r] = mask ? exp(E-mx[r])*inv[r]*adj[p][r] : 0  (elementwise) ---
__global__ __launch_bounds__(256) void k_attw(const unsigned short* __restrict__ e,
                                              unsigned short* __restrict__ attD,
                                              const unsigned short* __restrict__ adjbf,
                                              const float* __restrict__ adj,
                                              const float2* __restrict__ stats, int b0) {
  const size_t flat = (size_t)blockIdx.x * 256 + threadIdx.x; // x8 elems
  const int r = (int)((flat << 3) & (NN - 1));
  const size_t pg = flat >> 7; // gi*1024 + p
  const int gi = (int)(pg >> 10), p = (int)(pg & 1023);
  const int b = b0 + (gi >> 2);
  u16x8 ev = *(const u16x8*)(e + (pg << 10) + r);
  float av[8];
  if (adjbf) {
    u16x8 a8 = *(const u16x8*)(adjbf + ((size_t)b * NN + p) * NN + r);
#pragma unroll
    for (int j = 0; j < 8; ++j) av[j] = bf2f((unsigned short)a8[j]);
  } else {
    const float* ap = adj + ((size_t)b * NN + p) * NN + r;
    float4 a0 = *(const float4*)ap, a1 = *(const float4*)(ap + 4);
    av[0] = a0.x; av[1] = a0.y; av[2] = a0.z; av[3] = a0.w;
    av[4] = a1.x; av[5] = a1.y; av[6] = a1.z; av[7] = a1.w;
  }
  const float2* st = stats + ((size_t)gi << 10) + r;
  u16x8 o;
#pragma unroll
  for (int j = 0; j < 8; ++j) {
    float2 mi = st[j];
    o[j] = (av[j] > 0.f) ? f2bf(__expf(h2f((unsigned short)ev[j]) - mi.x) * mi.y * av[j])
                         : (unsigned short)0;
  }
  *(u16x8*)(attD + (pg << 10) + r) = o;
}

// ------- az3: acc[p][q] = sum_r att[p][r] * bT[q][r]  (direct frags, no LDS) ---
// az0 mode (h==null): outN = relu(acc). hop mode: outN = beta*h + (1-beta)*relu.
// outT (optional): transposed z copy for the next hop.
__global__ __launch_bounds__(256) void k_az3(const unsigned short* __restrict__ att,
                                             const unsigned short* __restrict__ bT,
                                             const unsigned short* __restrict__ h,
                                             const float* __restrict__ beta,
                                             unsigned short* __restrict__ outN,
                                             unsigned short* __restrict__ outT, int b0) {
  const int p0 = blockIdx.x * 64;
  const int gi = blockIdx.y;
  const int b = b0 + (gi >> 2), i = gi & 3;
  const int bi = b * HH + i;
  const int tid = threadIdx.x, w = tid >> 6, lane = tid & 63;
  const int l15 = lane & 15, kq = lane >> 4;
  const unsigned short* aRow =
      att + (size_t)gi * NN * NN + (size_t)(p0 + w * 16 + l15) * NN + kq * 8;
  const unsigned short* bRow = bT + (size_t)bi * 128 * NN + (size_t)l15 * NN + kq * 8;
  f32x4 acc[8] = {};
  for (int rc = 0; rc < NN; rc += 32) {
    bf16x8 a = *(const bf16x8*)(aRow + rc);
#pragma unroll
    for (int cb = 0; cb < 8; ++cb) {
      bf16x8 bf = *(const bf16x8*)(bRow + (size_t)(cb * 16) * NN + rc);
      acc[cb] = __builtin_amdgcn_mfma_f32_16x16x32_bf16(a, bf, acc[cb], 0, 0, 0);
    }
  }
  __shared__ unsigned short T[64][136];
#pragma unroll
  for (int cb = 0; cb < 8; ++cb)
#pragma unroll
    for (int rg = 0; rg < 4; ++rg)
      T[w * 16 + kq * 4 + rg][cb * 16 + l15] = f2bf(fmaxf(acc[cb][rg], 0.f));
  __syncthreads();
  const int row = tid >> 2, qc = (tid & 3) * 32;
  const int p = p0 + row;
  const size_t gbase = ((size_t)b * NN + p) * 512 + (size_t)i * 128 + qc;
  if (h) {
    const float bt = beta[((size_t)b * NN + p) * HH + i];
    const float om = 1.f - bt;
#pragma unroll
    for (int j = 0; j < 4; ++j) {
      u16x8 az = *(const u16x8*)&T[row][qc + j * 8];
      u16x8 hv = *(const u16x8*)(h + gbase + j * 8);
      u16x8 zv;
#pragma unroll
      for (int m2 = 0; m2 < 8; ++m2)
        zv[m2] = f2bf(bt * bf2f((unsigned short)hv[m2]) + om * bf2f((unsigned short)az[m2]));
      *(u16x8*)(outN + gbase + j * 8) = zv;
      *(u16x8*)&T[row][qc + j * 8] = zv;
    }
  } else {
#pragma unroll
    for (int j = 0; j < 4; ++j)
      *(u16x8*)(outN + gbase + j * 8) = *(const u16x8*)&T[row][qc + j * 8];
  }
  if (outT) {
    __syncthreads();
    const int q = tid >> 1, nc = (tid & 1) * 32;
    unsigned short* orow = outT + (size_t)bi * 128 * NN + (size_t)q * NN + p0 + nc;
#pragma unroll
    for (int c4 = 0; c4 < 4; ++c4) {
      u16x8 v;
#pragma unroll
      for (int j = 0; j < 8; ++j) v[j] = T[nc + c4 * 8 + j][q];
      *(u16x8*)(orow + c4 * 8) = v;
    }
  }
}

// ---------------- beta[idx] = sigmoid( h·Wb[:D] + az·Wb[D:] + bb ) -------------
__global__ __launch_bounds__(256) void k_beta(const unsigned short* __restrict__ h,
                                              const unsigned short* __restrict__ az,
                                              const float* __restrict__ Wbk,
                                              const float* __restrict__ bbk,
                                              float* __restrict__ beta, int base) {
  const int wid = threadIdx.x >> 6, lane = threadIdx.x & 63;
  const int idx = base + blockIdx.x * 4 + wid; // global (b*N+n)*H + i
  const unsigned short* hp = h + (size_t)idx * 128;
  const unsigned short* ap = az + (size_t)idx * 128;
  float s = 0.f;
#pragma unroll
  for (int e = 0; e < 2; ++e) {
    int d = lane + e * 64;
    s += bf2f(hp[d]) * Wbk[d] + bf2f(ap[d]) * Wbk[128 + d];
  }
#pragma unroll
  for (int off = 32; off; off >>= 1) s += __shfl_xor(s, off);
  if (lane == 0) beta[idx] = 1.f / (1.f + __expf(-(s + bbk[0])));
}

// ---- hop-1: z = beta*h + (1-beta)*az ; also writes zT when needed -------------
__global__ __launch_bounds__(256) void k_zupd1(const unsigned short* __restrict__ h,
                                               const unsigned short* __restrict__ az,
                                               const float* __restrict__ beta,
                                               unsigned short* __restrict__ z,
                                               unsigned short* __restrict__ zT, int b0) {
  const int p0 = blockIdx.x * 64;
  const int gi = blockIdx.y;
  const int b = b0 + (gi >> 2), i = gi & 3;
  const int bi = b * HH + i;
  const int tid = threadIdx.x;
  __shared__ unsigned short T[64][136];
  const int row = tid >> 2, qc = (tid & 3) * 32;
  const int p = p0 + row;
  const size_t gbase = ((size_t)b * NN + p) * 512 + (size_t)i * 128 + qc;
  const float bt = beta[((size_t)b * NN + p) * HH + i];
  const float om = 1.f - bt;
#pragma unroll
  for (int j = 0; j < 4; ++j) {
    u16x8 hv = *(const u16x8*)(h + gbase + j * 8);
    u16x8 av = *(const u16x8*)(az + gbase + j * 8);
    u16x8 zv;
#pragma unroll
    for (int m2 = 0; m2 < 8; ++m2)
      zv[m2] = f2bf(bt * bf2f((unsigned short)hv[m2]) + om * bf2f((unsigned short)av[m2]));
    *(u16x8*)(z + gbase + j * 8) = zv;
    if (zT) *(u16x8*)&T[row][qc + j * 8] = zv;
  }
  if (zT) {
    __syncthreads();
    const int q = tid >> 1, nc = (tid & 1) * 32;
    unsigned short* orow = zT + (size_t)bi * 128 * NN + (size_t)q * NN + p0 + nc;
#pragma unroll
    for (int c4 = 0; c4 < 4; ++c4) {
      u16x8 v;
#pragma unroll
      for (int j = 0; j < 8; ++j) v[j] = T[nc + c4 * 8 + j][q];
      *(u16x8*)(orow + c4 * 8) = v;
    }
  }
}

// -------- out[n,d] = mean_i z[n,i,d] (- c1); c fp32 (+bf16); pre-offset --------
__global__ __launch_bounds__(256) void k_headmean(const unsigned short* __restrict__ z,
                                                  const float* __restrict__ c1,
                                                  float* __restrict__ outp,
                                                  unsigned short* __restrict__ outbf) {
  const int idx = blockIdx.x * 256 + threadIdx.x; // over group's N*D
  const int d = idx & 127, bn = idx >> 7;
  const size_t base = (size_t)bn * 512 + d;
  float v = 0.25f * (bf2f(z[base]) + bf2f(z[base + 128]) +
                     bf2f(z[base + 256]) + bf2f(z[base + 384]));
  if (c1) v -= c1[idx];
  outp[idx] = v;
  if (outbf) outbf[idx] = f2bf(v);
}

// ---------------- node mean + MLP head ----------------------------------------
__global__ __launch_bounds__(128) void k_final(const float* __restrict__ c,
                                               const float* __restrict__ valid,
                                               const float* __restrict__ Wfc0,
                                               const float* __restrict__ bfc0,
                                               const float* __restrict__ Wfcm,
                                               const float* __restrict__ bfcm,
                                               const float* __restrict__ Wfcl,
                                               const float* __restrict__ bfcl,
                                               float* __restrict__ out) {
  const int b = blockIdx.x, d = threadIdx.x;
  __shared__ float bufA[128], bufB[128], red[128];
  float s = 0.f, vs = 0.f;
  for (int n = 0; n < NN; ++n) {
    float vv = valid[b * NN + n];
    s += c[((size_t)b * NN + n) * 128 + d] * vv;
    vs += vv;
  }
  bufA[d] = s / vs;
  __syncthreads();
  float t = bfc0[d];
  for (int m = 0; m < 128; ++m) t += bufA[m] * Wfc0[m * 128 + d];
  bufB[d] = fmaxf(t, 0.f);
  __syncthreads();
  t = bfcm[d];
  for (int m = 0; m < 128; ++m) t += bufB[m] * Wfcm[m * 128 + d];
  bufA[d] = fmaxf(t, 0.f);
  __syncthreads();
  t = bfcm[128 + d];
  for (int m = 0; m < 128; ++m) t += bufA[m] * Wfcm[128 * 128 + m * 128 + d];
  bufB[d] = fmaxf(t, 0.f);
  __syncthreads();
  red[d] = bufB[d] * Wfcl[d];
  __syncthreads();
  for (int st = 64; st; st >>= 1) {
    if (d < st) red[d] += red[d + st];
    __syncthreads();
  }
  if (d == 0) out[b] = 1.f / (1.f + __expf(-(red[0] + bfcl[0])));
}

extern "C" void kernel_launch(void* const* d_in, const int* in_sizes, int n_in,
                              void* d_out, int out_size, void* d_ws, size_t ws_size,
                              hipStream_t stream) {
  (void)in_sizes; (void)n_in; (void)out_size;
  const float* x     = (const float*)d_in[0];
  const float* adj1  = (const float*)d_in[1];
  const float* adj2  = (const float*)d_in[2];
  const float* valid = (const float*)d_in[3];
  const float* Wemb  = (const float*)d_in[4];
  const float* Wh    = (const float*)d_in[5];
  const float* bh    = (const float*)d_in[6];
  const float* We    = (const float*)d_in[7];
  const float* Wb    = (const float*)d_in[8];
  const float* bb    = (const float*)d_in[9];
  const float* Wfc0  = (const float*)d_in[10];
  const float* bfc0  = (const float*)d_in[11];
  const float* Wfcm  = (const float*)d_in[12];
  const float* bfcm  = (const float*)d_in[13];
  const float* Wfcl  = (const float*)d_in[14];
  const float* bfcl  = (const float*)d_in[15];
  float* out = (float*)d_out;

  // ---- workspace (fp32-element offsets) ----
  float* w = (float*)d_ws;
  size_t off = 0;
  float* c    = w + off; off += (size_t)BB * NN * DD;        // 4 MB
  float* c1   = w + off; off += (size_t)BB * NN * DD;        // 4 MB
  float* beta = w + off; off += (size_t)BB * NN * HH;
  float2* stats = (float2*)(w + off); off += (size_t)BB * HH * NN * 2;
  unsigned short* c_bf = (unsigned short*)(w + off); off += (size_t)BB * NN * DD / 2;
  unsigned short* h_bf = (unsigned short*)(w + off); off += (size_t)BB * NN * HH * DD / 2;
  unsigned short* g_bf = (unsigned short*)(w + off); off += (size_t)BB * NN * HH * DD / 2;
  unsigned short* zA   = (unsigned short*)(w + off); off += (size_t)BB * NN * HH * DD / 2;
  unsigned short* zB   = (unsigned short*)(w + off); off += (size_t)BB * NN * HH * DD / 2;
  unsigned short* azb  = (unsigned short*)(w + off); off += (size_t)BB * NN * HH * DD / 2;
  unsigned short* hT   = (unsigned short*)(w + off); off += (size_t)BB * HH * DD * NN / 2;
  unsigned short* zTA  = (unsigned short*)(w + off); off += (size_t)BB * HH * DD * NN / 2;
  unsigned short* zTB  = (unsigned short*)(w + off); off += (size_t)BB * HH * DD * NN / 2;
  unsigned short* WhT  = (unsigned short*)(w + off); off += (size_t)LL * 512 * 128 / 2;
  unsigned short* WeT  = (unsigned short*)(w + off); off += (size_t)LL * 128 * 128 / 2;
  const size_t fixedF = off;
  const size_t adjBufF = (size_t)BB * NN * NN / 2;   // one bf16 adj buffer, in floats
  const size_t adjF = 4 * adjBufF;                    // adjT1/2 + adjbf1/2
  const size_t eF = (size_t)HH * NN * NN / 2;         // per-batch e group, in floats
  const size_t wsF = ws_size / sizeof(float);

  int G = 8;
  bool useAdj = true;
  while (G > 1 && fixedF + adjF + (size_t)G * eF > wsF) G >>= 1;
  if (fixedF + adjF + (size_t)G * eF > wsF) {
    useAdj = false;
    G = 8;
    while (G > 1 && fixedF + (size_t)G * eF > wsF) G >>= 1;
  }
  const bool eOnce = useAdj && (fixedF + adjF + 2ull * G * eF <= wsF);

  size_t p2 = fixedF;
  unsigned short *adjT1 = nullptr, *adjT2 = nullptr, *adjbf1 = nullptr, *adjbf2 = nullptr;
  if (useAdj) {
    adjT1  = (unsigned short*)(w + p2); p2 += adjBufF;
    adjT2  = (unsigned short*)(w + p2); p2 += adjBufF;
    adjbf1 = (unsigned short*)(w + p2); p2 += adjBufF;
    adjbf2 = (unsigned short*)(w + p2); p2 += adjBufF;
  }
  unsigned short* e = (unsigned short*)(w + p2); p2 += (size_t)G * eF;
  unsigned short* attB = eOnce ? (unsigned short*)(w + p2) : e;

  if (useAdj) {
    k_transpose_bf16<<<dim3(32, 32, BB), 256, 0, stream>>>(adj1, adjT1);
    k_transpose_bf16<<<dim3(32, 32, BB), 256, 0, stream>>>(adj2, adjT2);
    k_copy_bf16<<<BB * NN * NN / 1024, 256, 0, stream>>>(adj1, adjbf1);
    k_copy_bf16<<<BB * NN * NN / 1024, 256, 0, stream>>>(adj2, adjbf2);
  }
  k_wtrans<<<dim3(4, 16, LL), 256, 0, stream>>>(Wh, WhT, 512);
  k_wtrans<<<dim3(4, 4, LL), 256, 0, stream>>>(We, WeT, 128);
  k_gemm_k128<<<dim3(128, 2), 256, 0, stream>>>(x, Wemb, c, c_bf, BB * NN, DD);

  for (int k = 0; k < LL; ++k) {
    // h, g are branch-invariant: compute once per layer
    k_gemm_nt<<<dim3(128, 8), 256, 0, stream>>>(
        c_bf, WhT + (size_t)k * 512 * 128, bh + (size_t)k * 512, h_bf, hT, 512);
    k_gemm_nt<<<dim3(512, 2), 256, 0, stream>>>(
        h_bf, WeT + (size_t)k * 128 * 128, nullptr, g_bf, nullptr, 128);
    for (int b0 = 0; b0 < BB; b0 += G) {
      if (eOnce) k_e2<<<dim3(16, 16, G * HH), 256, 0, stream>>>(g_bf, h_bf, e, b0);
      for (int br = 0; br < 2; ++br) {
        const float* adjcur = (br == 0) ? adj1 : adj2;
        const unsigned short* adjTcur = useAdj ? ((br == 0) ? adjT1 : adjT2) : nullptr;
        const unsigned short* adjbfcur = useAdj ? ((br == 0) ? adjbf1 : adjbf2) : nullptr;
        if (!eOnce) k_e2<<<dim3(16, 16, G * HH), 256, 0, stream>>>(g_bf, h_bf, e, b0);
        k_stats<<<G * HH * NN, 128, 0, stream>>>(e, adjTcur, adjcur, stats, b0);
        k_attw<<<G * 2048, 256, 0, stream>>>(e, attB, adjbfcur, adjcur, stats, b0);
        k_az3<<<dim3(16, G * HH), 256, 0, stream>>>(attB, hT, nullptr, nullptr, azb,
                                                    nullptr, b0);
        k_beta<<<G * NN * HH / 4, 256, 0, stream>>>(
            h_bf, azb, Wb + (size_t)k * 2 * DD, bb + k, beta, b0 * NN * HH);
        k_zupd1<<<dim3(16, G * HH), 256, 0, stream>>>(
            h_bf, azb, beta, zA, (k >= 1) ? zTA : nullptr, b0);
        unsigned short *cur = zA, *curT = zTA, *nxt = zB, *nxtT = zTB;
        for (int t = 2; t <= k + 1; ++t) {
          k_az3<<<dim3(16, G * HH), 256, 0, stream>>>(
              attB, curT, h_bf, beta, nxt, (t < k + 1) ? nxtT : nullptr, b0);
          unsigned short* tm1 = cur; cur = nxt; nxt = tm1;
          unsigned short* tm2 = curT; curT = nxtT; nxtT = tm2;
        }
        const size_t oH = (size_t)b0 * NN * 512;
        const size_t oC = (size_t)b0 * NN * DD;
        k_headmean<<<G * 512, 256, 0, stream>>>(
            cur + oH, (br == 0) ? nullptr : (c1 + oC), ((br == 0) ? c1 : c) + oC,
            (br == 0) ? nullptr : (c_bf + oC));
      }
    }
  }
  k_final<<<BB, 128, 0, stream>>>(c, valid, Wfc0, bfc0, Wfcm, bfcm, Wfcl, bfcl, out);
}

// Round 6
// 1418.079 us; speedup vs baseline: 2.5416x; 2.5416x over previous
//
#include <hip/hip_runtime.h>
#include <hip/hip_bf16.h>

#define BB 8
#define NN 1024
#define DD 128
#define HH 4
#define LL 4

typedef __attribute__((ext_vector_type(8))) short bf16x8;
typedef __attribute__((ext_vector_type(4))) float f32x4;
typedef __attribute__((ext_vector_type(8))) unsigned short u16x8;

__device__ __forceinline__ unsigned short f2bf(float f) {
  union { float f; unsigned int u; } v; v.f = f;
  unsigned int u = v.u;
  return (unsigned short)((u + 0x7FFFu + ((u >> 16) & 1u)) >> 16);
}
__device__ __forceinline__ float bf2f(unsigned short s) {
  union { unsigned int u; float f; } v; v.u = ((unsigned int)s) << 16;
  return v.f;
}
__device__ __forceinline__ unsigned short f2h(float f) {
  union { _Float16 h; unsigned short u; } v; v.h = (_Float16)f;
  return v.u;
}
__device__ __forceinline__ float h2f(unsigned short u) {
  union { unsigned short u; _Float16 h; } v; v.u = u;
  return (float)v.h;
}

// ------- maskT bits: maskW[b][r][word w] bit t = (adj[b][p=32w+t][r] > 0) ------
__global__ __launch_bounds__(256) void k_maskT(const float* __restrict__ in,
                                               unsigned int* __restrict__ maskW) {
  __shared__ float t[32][33];
  int b = blockIdx.z;
  int x0 = blockIdx.x * 32, y0 = blockIdx.y * 32;
  int tx = threadIdx.x & 31, ty = threadIdx.x >> 5;
  const float* ib = in + (size_t)b * NN * NN;
#pragma unroll
  for (int j = 0; j < 32; j += 8)
    t[ty + j][tx] = ib[(size_t)(y0 + ty + j) * NN + x0 + tx];
  __syncthreads();
  const int half = (threadIdx.x >> 5) & 1;
#pragma unroll
  for (int j = 0; j < 32; j += 8) {
    bool nz = t[tx][ty + j] > 0.f; // value at transposed (row=x0+ty+j, col=y0+tx)
    unsigned long long bl = __ballot(nz);
    unsigned int word = half ? (unsigned int)(bl >> 32) : (unsigned int)bl;
    if (tx == 0)
      maskW[((size_t)b * NN + x0 + ty + j) * 32 + (y0 >> 5)] = word;
  }
}

// ---------------- fp32 -> bf16 copy (adj row-major values for attw) ------------
__global__ __launch_bounds__(256) void k_copy_bf16(const float* __restrict__ in,
                                                   unsigned short* __restrict__ out) {
  int idx = blockIdx.x * 256 + threadIdx.x; // 4 floats per thread
  float4 v = ((const float4*)in)[idx];
  uint2 pv;
  pv.x = (unsigned int)f2bf(v.x) | ((unsigned int)f2bf(v.y) << 16);
  pv.y = (unsigned int)f2bf(v.z) | ((unsigned int)f2bf(v.w) << 16);
  ((uint2*)out)[idx] = pv;
}

// ------- weight transpose: in [nm][128][Nn] fp32 -> out [nm][Nn][128] bf16 -----
__global__ __launch_bounds__(256) void k_wtrans(const float* __restrict__ in,
                                                unsigned short* __restrict__ out, int Nn) {
  __shared__ float t[32][33];
  int m = blockIdx.z;
  const float* ib = in + (size_t)m * 128 * Nn;
  unsigned short* ob = out + (size_t)m * Nn * 128;
  int k0 = blockIdx.x * 32, n0 = blockIdx.y * 32;
  int tx = threadIdx.x & 31, ty = threadIdx.x >> 5;
#pragma unroll
  for (int j = 0; j < 32; j += 8)
    t[ty + j][tx] = ib[(size_t)(k0 + ty + j) * Nn + n0 + tx];
  __syncthreads();
#pragma unroll
  for (int j = 0; j < 32; j += 8)
    ob[(size_t)(n0 + ty + j) * 128 + k0 + tx] = f2bf(t[tx][ty + j]);
}

// ------- SIMT K=128 GEMM (embed only): C = A[M,128] @ Bw[128,Nn]; fp32+bf16 ----
__global__ __launch_bounds__(256) void k_gemm_k128(const float* __restrict__ A,
                                                   const float* __restrict__ Bw,
                                                   float* __restrict__ C,
                                                   unsigned short* __restrict__ Cbf,
                                                   int M, int Nn) {
  __shared__ __align__(16) float As[32][68];
  __shared__ __align__(16) float Bs[32][68];
  const int tm = blockIdx.x * 64, tn = blockIdx.y * 64;
  const int tid = threadIdx.x;
  const int ty = tid >> 4, tx = tid & 15;
  float acc[4][4] = {};
  for (int kc = 0; kc < 128; kc += 32) {
#pragma unroll
    for (int e = 0; e < 8; ++e) {
      int fl = tid + e * 256;
      int r = fl >> 5, k = fl & 31;
      As[k][r] = A[(size_t)(tm + r) * 128 + kc + k];
    }
#pragma unroll
    for (int e = 0; e < 8; ++e) {
      int fl = tid + e * 256;
      int k = fl >> 6, n = fl & 63;
      Bs[k][n] = Bw[(size_t)(kc + k) * Nn + tn + n];
    }
    __syncthreads();
#pragma unroll
    for (int kk = 0; kk < 32; ++kk) {
      float a4[4], b4[4];
      *(float4*)a4 = *(const float4*)&As[kk][ty * 4];
      *(float4*)b4 = *(const float4*)&Bs[kk][tx * 4];
#pragma unroll
      for (int i = 0; i < 4; ++i)
#pragma unroll
        for (int j = 0; j < 4; ++j) acc[i][j] += a4[i] * b4[j];
    }
    __syncthreads();
  }
#pragma unroll
  for (int i = 0; i < 4; ++i) {
    size_t base = (size_t)(tm + ty * 4 + i) * Nn + tn + tx * 4;
    *(float4*)&C[base] = *(float4*)acc[i];
    uint2 pv;
    pv.x = (unsigned int)f2bf(acc[i][0]) | ((unsigned int)f2bf(acc[i][1]) << 16);
    pv.y = (unsigned int)f2bf(acc[i][2]) | ((unsigned int)f2bf(acc[i][3]) << 16);
    *(uint2*)&Cbf[base] = pv;
  }
}

// ------- MFMA NT GEMM, K=128: out[M,Nn](bf16) = A[M,128](bf16) @ Bt[Nn,128]^T --
// When hT != null (Nn==512 h-gemm): also write hT[b,i][q][node] transposed copy.
__global__ __launch_bounds__(256) void k_gemm_nt(const unsigned short* __restrict__ A,
                                                 const unsigned short* __restrict__ Bt,
                                                 const float* __restrict__ bias,
                                                 unsigned short* __restrict__ outp,
                                                 unsigned short* __restrict__ hT,
                                                 int Nn) {
  const int m0 = blockIdx.x * 64, n0 = blockIdx.y * 64;
  const int tid = threadIdx.x;
  const int wave = tid >> 6, lane = tid & 63;
  const int l15 = lane & 15, kq = lane >> 4;
  __shared__ __align__(16) unsigned short O[64][72];
  const unsigned short* aP = A + (size_t)(m0 + wave * 16 + l15) * 128;
  f32x4 acc[4] = {};
#pragma unroll
  for (int kk = 0; kk < 4; ++kk) {
    bf16x8 aF = *(const bf16x8*)(aP + (kk * 4 + kq) * 8);
#pragma unroll
    for (int cb = 0; cb < 4; ++cb) {
      bf16x8 bF = *(const bf16x8*)(Bt + (size_t)(n0 + cb * 16 + l15) * 128 + (kk * 4 + kq) * 8);
      acc[cb] = __builtin_amdgcn_mfma_f32_16x16x32_bf16(aF, bF, acc[cb], 0, 0, 0);
    }
  }
#pragma unroll
  for (int cb = 0; cb < 4; ++cb) {
    float bv = bias ? bias[n0 + cb * 16 + l15] : 0.f;
#pragma unroll
    for (int rg = 0; rg < 4; ++rg)
      O[wave * 16 + kq * 4 + rg][cb * 16 + l15] = f2bf(acc[cb][rg] + bv);
  }
  if (hT) { // transposed copy, direct from regs: 4 consecutive nodes per lane
    const int b = m0 >> 10;
    const int head = n0 >> 7, q0 = n0 & 127;
    unsigned short* hb2 = hT + (size_t)(b * HH + head) * 128 * NN;
#pragma unroll
    for (int cb = 0; cb < 4; ++cb) {
      float bv = bias ? bias[n0 + cb * 16 + l15] : 0.f;
      int q = q0 + cb * 16 + l15;
      uint2 pv;
      pv.x = (unsigned int)f2bf(acc[cb][0] + bv) | ((unsigned int)f2bf(acc[cb][1] + bv) << 16);
      pv.y = (unsigned int)f2bf(acc[cb][2] + bv) | ((unsigned int)f2bf(acc[cb][3] + bv) << 16);
      *(uint2*)(hb2 + (size_t)q * NN + (m0 & 1023) + wave * 16 + kq * 4) = pv;
    }
  }
  __syncthreads();
#pragma unroll
  for (int it = 0; it < 2; ++it) {
    int row = (tid >> 3) + it * 32, ch = tid & 7;
    *(uint4*)&outp[(size_t)(m0 + row) * Nn + n0 + ch * 8] = *(uint4*)&O[row][ch * 8];
  }
}

// ------- E tile via MFMA -> fp16 [p][r]: e = g[p]·h[r] + h[p]·g[r] (symmetric) -
// A-frags direct from global (amortized); B tiles staged in 32KB swizzled LDS.
__global__ __launch_bounds__(256) void k_e_st(const unsigned short* __restrict__ g,
                                              const unsigned short* __restrict__ h,
                                              unsigned short* __restrict__ e, int b0) {
  const int tp = blockIdx.x, tr = blockIdx.y;
  if (tp > tr) return;
  const int gi = blockIdx.z;
  const int b = b0 + (gi >> 2), i = gi & 3;
  const int p0 = tp * 64, r0 = tr * 64;
  const bool diag = (tp == tr);
  __shared__ __align__(16) char lds[32768];
  const int tid = threadIdx.x;
  const unsigned short* gb = g + (size_t)b * NN * 512 + i * 128;
  const unsigned short* hb = h + (size_t)b * NN * 512 + i * 128;
  // stage B tiles: [0]=Gr, [16384]=Hr ; row-local 256B, chunk^(row&7) swizzle
#pragma unroll
  for (int e2 = 0; e2 < 8; ++e2) {
    int fl = tid + e2 * 256;        // 0..2047
    int t = fl >> 10, rem = fl & 1023;
    int row = rem >> 4, ch = rem & 15;
    const unsigned short* src = t ? hb : gb;
    uint4 v = *(const uint4*)(src + (size_t)(r0 + row) * 512 + ch * 8);
    *(uint4*)(lds + t * 16384 + row * 256 + ((ch ^ (row & 7)) * 16)) = v;
  }
  __syncthreads();
  const int wave = tid >> 6, lane = tid & 63;
  const int l15 = lane & 15, kq = lane >> 4;
  const unsigned short* aG = gb + (size_t)(p0 + wave * 16 + l15) * 512;
  const unsigned short* aH = hb + (size_t)(p0 + wave * 16 + l15) * 512;
  f32x4 acc[4] = {};
#pragma unroll
  for (int kk = 0; kk < 4; ++kk) {
    bf16x8 gA = *(const bf16x8*)(aG + (kk * 4 + kq) * 8);
    bf16x8 hA = *(const bf16x8*)(aH + (kk * 4 + kq) * 8);
#pragma unroll
    for (int cb = 0; cb < 4; ++cb) {
      int row = cb * 16 + l15;
      int chs = ((kk * 4 + kq) ^ (row & 7)) * 16;
      bf16x8 gB = *(const bf16x8*)(lds + row * 256 + chs);
      bf16x8 hB = *(const bf16x8*)(lds + 16384 + row * 256 + chs);
      acc[cb] = __builtin_amdgcn_mfma_f32_16x16x32_bf16(gA, hB, acc[cb], 0, 0, 0);
      acc[cb] = __builtin_amdgcn_mfma_f32_16x16x32_bf16(hA, gB, acc[cb], 0, 0, 0);
    }
  }
  __syncthreads(); // B tiles consumed; reuse LDS for retile
  unsigned short* eN = (unsigned short*)lds;   // [64][72] fp16
  unsigned short* eT = eN + 64 * 72;
#pragma unroll
  for (int cb = 0; cb < 4; ++cb)
#pragma unroll
    for (int rg = 0; rg < 4; ++rg) {
      const int pl = wave * 16 + kq * 4 + rg, rl = cb * 16 + l15;
      const unsigned short v = f2h(acc[cb][rg]);
      eN[pl * 72 + rl] = v;
      if (!diag) eT[rl * 72 + pl] = v;
    }
  __syncthreads();
  unsigned short* eb = e + (size_t)gi * NN * NN;
#pragma unroll
  for (int it = 0; it < 2; ++it) {
    const int row = (tid >> 3) + it * 32, ch = tid & 7;
    *(uint4*)&eb[(size_t)(p0 + row) * NN + r0 + ch * 8] = *(uint4*)&eN[row * 72 + ch * 8];
    if (!diag)
      *(uint4*)&eb[(size_t)(r0 + row) * NN + p0 + ch * 8] = *(uint4*)&eT[row * 72 + ch * 8];
  }
}

// ------- per-column softmax stats via maskT bits: mx[r], inv[r] ----------------
__global__ __launch_bounds__(128) void k_stats(const unsigned short* __restrict__ e,
                                               const unsigned int* __restrict__ maskW,
                                               float2* __restrict__ stats, int b0) {
  const int col = blockIdx.x; // gi*N + r
  const int r = col & (NN - 1);
  const int gi = col >> 10;
  const int b = b0 + (gi >> 2);
  const unsigned short* erow = e + (size_t)col * NN;
  const int tid = threadIdx.x;
  u16x8 ev = *(const u16x8*)(erow + tid * 8);
  unsigned int word = maskW[((size_t)b * NN + r) * 32 + (tid >> 2)];
  unsigned int byte = (word >> ((tid & 3) * 8)) & 0xffu;
  float s[8];
#pragma unroll
  for (int j = 0; j < 8; ++j)
    s[j] = ((byte >> j) & 1u) ? h2f((unsigned short)ev[j]) : 0.f;
  float mx = s[0];
#pragma unroll
  for (int j = 1; j < 8; ++j) mx = fmaxf(mx, s[j]);
#pragma unroll
  for (int o = 32; o; o >>= 1) mx = fmaxf(mx, __shfl_xor(mx, o));
  __shared__ float sm[2], ss[2];
  const int wv = tid >> 6, ln = tid & 63;
  if (ln == 0) sm[wv] = mx;
  __syncthreads();
  mx = fmaxf(sm[0], sm[1]);
  float ps = 0.f;
#pragma unroll
  for (int j = 0; j < 8; ++j) ps += __expf(s[j] - mx); // masked -> exp(0-mx)
#pragma unroll
  for (int o = 32; o; o >>= 1) ps += __shfl_xor(ps, o);
  if (ln == 0) ss[wv] = ps;
  __syncthreads();
  if (tid == 0) stats[col] = make_float2(mx, 1.f / (ss[0] + ss[1]));
}

// ------- att[p][r] = mask ? exp(E-mx[r])*inv[r]*adj[p][r] : 0  (elementwise) ---
__global__ __launch_bounds__(256) void k_attw(const unsigned short* __restrict__ e,
                                              unsigned short* __restrict__ attD,
                                              const unsigned short* __restrict__ adjbf,
                                              const float* __restrict__ adj,
                                              const float2* __restrict__ stats, int b0) {
  const size_t flat = (size_t)blockIdx.x * 256 + threadIdx.x; // x8 elems
  const int r = (int)((flat << 3) & (NN - 1));
  const size_t pg = flat >> 7; // gi*1024 + p
  const int gi = (int)(pg >> 10), p = (int)(pg & 1023);
  const int b = b0 + (gi >> 2);
  u16x8 ev = *(const u16x8*)(e + (pg << 10) + r);
  float av[8];
  if (adjbf) {
    u16x8 a8 = *(const u16x8*)(adjbf + ((size_t)b * NN + p) * NN + r);
#pragma unroll
    for (int j = 0; j < 8; ++j) av[j] = bf2f((unsigned short)a8[j]);
  } else {
    const float* ap = adj + ((size_t)b * NN + p) * NN + r;
    float4 a0 = *(const float4*)ap, a1 = *(const float4*)(ap + 4);
    av[0] = a0.x; av[1] = a0.y; av[2] = a0.z; av[3] = a0.w;
    av[4] = a1.x; av[5] = a1.y; av[6] = a1.z; av[7] = a1.w;
  }
  const float2* st = stats + ((size_t)gi << 10) + r;
  u16x8 o;
#pragma unroll
  for (int j = 0; j < 8; ++j) {
    float2 mi = st[j];
    o[j] = (av[j] > 0.f) ? f2bf(__expf(h2f((unsigned short)ev[j]) - mi.x) * mi.y * av[j])
                         : (unsigned short)0;
  }
  *(u16x8*)(attD + (pg << 10) + r) = o;
}

// ---- hWb[b,n,i] = sum_d h[b,n,i,d] * Wb_k[d]  (per layer) ---------------------
__global__ __launch_bounds__(256) void k_hwb(const unsigned short* __restrict__ h,
                                             const float* __restrict__ Wbk,
                                             float* __restrict__ hWb) {
  const int wid = threadIdx.x >> 6, lane = threadIdx.x & 63;
  const int idx = blockIdx.x * 4 + wid;
  const unsigned short* hp = h + (size_t)idx * 128;
  float s = 0.f;
#pragma unroll
  for (int e = 0; e < 2; ++e) {
    int d = lane + e * 64;
    s += bf2f(hp[d]) * Wbk[d];
  }
#pragma unroll
  for (int o = 32; o; o >>= 1) s += __shfl_xor(s, o);
  if (lane == 0) hWb[idx] = s;
}

// ---- az3 v2: acc[p][q] = sum_r att[p][r] * bT[q][r]  (staged, swizzled) -------
// MODE 0: az0 — compute beta in-kernel (hWb + az·Wb2 + bb), write beta, mix -> z
// MODE 1: hop — read beta, mix -> z.  Both write outN (+optional outT).
template <int MODE>
__global__ __launch_bounds__(256) void k_az3(const unsigned short* __restrict__ att,
                                             const unsigned short* __restrict__ bT,
                                             const unsigned short* __restrict__ h,
                                             const float* __restrict__ hWb,
                                             const float* __restrict__ Wbk,
                                             const float* __restrict__ bbk,
                                             float* __restrict__ betaBuf,
                                             unsigned short* __restrict__ outN,
                                             unsigned short* __restrict__ outT, int b0) {
  const int p0 = blockIdx.x * 64;
  const int gi = blockIdx.y;
  const int b = b0 + (gi >> 2), i = gi & 3;
  const int bi = b * HH + i;
  const int tid = threadIdx.x, w = tid >> 6, lane = tid & 63;
  const int l15 = lane & 15, kq = lane >> 4;
  __shared__ __align__(16) char lds[24576]; // A 8KB | B 16KB ; T overlays after
  const unsigned short* aBase = att + (size_t)gi * NN * NN;
  const unsigned short* bBase = bT + (size_t)bi * 128 * NN;
  f32x4 acc[8] = {};
  for (int rc = 0; rc < NN; rc += 64) {
    __syncthreads();
#pragma unroll
    for (int s = 0; s < 2; ++s) { // A: 64 rows x 8 granules of 16B
      int fl = tid + s * 256;
      int row = fl >> 3, g2 = fl & 7;
      uint4 v = *(const uint4*)(aBase + (size_t)(p0 + row) * NN + rc + g2 * 8);
      *(uint4*)(lds + row * 128 + ((g2 ^ (row & 7)) * 16)) = v;
    }
#pragma unroll
    for (int s = 0; s < 4; ++s) { // B: 128 rows x 8 granules
      int fl = tid + s * 256;
      int q = fl >> 3, g2 = fl & 7;
      uint4 v = *(const uint4*)(bBase + (size_t)q * NN + rc + g2 * 8);
      *(uint4*)(lds + 8192 + q * 128 + ((g2 ^ (q & 7)) * 16)) = v;
    }
    __syncthreads();
#pragma unroll
    for (int kk = 0; kk < 2; ++kk) {
      const int ar = w * 16 + l15;
      bf16x8 a = *(const bf16x8*)(lds + ar * 128 + (((kk * 4 + kq) ^ (ar & 7)) * 16));
#pragma unroll
      for (int cb = 0; cb < 8; ++cb) {
        const int br = cb * 16 + l15;
        bf16x8 bf = *(const bf16x8*)(lds + 8192 + br * 128 + (((kk * 4 + kq) ^ (br & 7)) * 16));
        acc[cb] = __builtin_amdgcn_mfma_f32_16x16x32_bf16(a, bf, acc[cb], 0, 0, 0);
      }
    }
  }
  __syncthreads();
  unsigned short* T = (unsigned short*)lds; // [64][136] relu'd az (pre-mix)
#pragma unroll
  for (int cb = 0; cb < 8; ++cb)
#pragma unroll
    for (int rg = 0; rg < 4; ++rg)
      T[(w * 16 + kq * 4 + rg) * 136 + cb * 16 + l15] = f2bf(fmaxf(acc[cb][rg], 0.f));
  __syncthreads();
  const int row = tid >> 2, qc = (tid & 3) * 32;
  const int p = p0 + row;
  const size_t gidx = ((size_t)b * NN + p) * HH + i;
  const size_t gbase = ((size_t)b * NN + p) * 512 + (size_t)i * 128 + qc;
  float bt;
  if (MODE == 0) {
    float part = 0.f;
#pragma unroll
    for (int j = 0; j < 32; ++j) part += bf2f(T[row * 136 + qc + j]) * Wbk[128 + qc + j];
    part += __shfl_xor(part, 1);
    part += __shfl_xor(part, 2); // full 128-dim sum across the quad
    bt = 1.f / (1.f + __expf(-(hWb[gidx] + part + bbk[0])));
    if ((tid & 3) == 0) betaBuf[gidx] = bt;
  } else {
    bt = betaBuf[gidx];
  }
  const float om = 1.f - bt;
#pragma unroll
  for (int j = 0; j < 4; ++j) {
    u16x8 az = *(const u16x8*)&T[row * 136 + qc + j * 8];
    u16x8 hv = *(const u16x8*)(h + gbase + j * 8);
    u16x8 zv;
#pragma unroll
    for (int m2 = 0; m2 < 8; ++m2)
      zv[m2] = f2bf(bt * bf2f((unsigned short)hv[m2]) + om * bf2f((unsigned short)az[m2]));
    *(u16x8*)(outN + gbase + j * 8) = zv;
    *(u16x8*)&T[row * 136 + qc + j * 8] = zv; // own slice only: no race
  }
  if (outT) {
    __syncthreads();
    const int q = tid >> 1, nc = (tid & 1) * 32;
    unsigned short* orow = outT + (size_t)bi * 128 * NN + (size_t)q * NN + p0 + nc;
#pragma unroll
    for (int c4 = 0; c4 < 4; ++c4) {
      u16x8 v;
#pragma unroll
      for (int j = 0; j < 8; ++j) v[j] = T[(nc + c4 * 8 + j) * 136 + q];
      *(u16x8*)(orow + c4 * 8) = v;
    }
  }
}

// -------- out[n,d] = mean_i z[n,i,d] (- c1); c fp32 (+bf16); pre-offset --------
__global__ __launch_bounds__(256) void k_headmean(const unsigned short* __restrict__ z,
                                                  const float* __restrict__ c1,
                                                  float* __restrict__ outp,
                                                  unsigned short* __restrict__ outbf) {
  const int idx = blockIdx.x * 256 + threadIdx.x; // over group's N*D
  const int d = idx & 127, bn = idx >> 7;
  const size_t base = (size_t)bn * 512 + d;
  float v = 0.25f * (bf2f(z[base]) + bf2f(z[base + 128]) +
                     bf2f(z[base + 256]) + bf2f(z[base + 384]));
  if (c1) v -= c1[idx];
  outp[idx] = v;
  if (outbf) outbf[idx] = f2bf(v);
}

// ---------------- node mean + MLP head ----------------------------------------
__global__ __launch_bounds__(128) void k_final(const float* __restrict__ c,
                                               const float* __restrict__ valid,
                                               const float* __restrict__ Wfc0,
                                               const float* __restrict__ bfc0,
                                               const float* __restrict__ Wfcm,
                                               const float* __restrict__ bfcm,
                                               const float* __restrict__ Wfcl,
                                               const float* __restrict__ bfcl,
                                               float* __restrict__ out) {
  const int b = blockIdx.x, d = threadIdx.x;
  __shared__ float bufA[128], bufB[128], red[128];
  float s = 0.f, vs = 0.f;
  for (int n = 0; n < NN; ++n) {
    float vv = valid[b * NN + n];
    s += c[((size_t)b * NN + n) * 128 + d] * vv;
    vs += vv;
  }
  bufA[d] = s / vs;
  __syncthreads();
  float t = bfc0[d];
  for (int m = 0; m < 128; ++m) t += bufA[m] * Wfc0[m * 128 + d];
  bufB[d] = fmaxf(t, 0.f);
  __syncthreads();
  t = bfcm[d];
  for (int m = 0; m < 128; ++m) t += bufB[m] * Wfcm[m * 128 + d];
  bufA[d] = fmaxf(t, 0.f);
  __syncthreads();
  t = bfcm[128 + d];
  for (int m = 0; m < 128; ++m) t += bufA[m] * Wfcm[128 * 128 + m * 128 + d];
  bufB[d] = fmaxf(t, 0.f);
  __syncthreads();
  red[d] = bufB[d] * Wfcl[d];
  __syncthreads();
  for (int st = 64; st; st >>= 1) {
    if (d < st) red[d] += red[d + st];
    __syncthreads();
  }
  if (d == 0) out[b] = 1.f / (1.f + __expf(-(red[0] + bfcl[0])));
}

extern "C" void kernel_launch(void* const* d_in, const int* in_sizes, int n_in,
                              void* d_out, int out_size, void* d_ws, size_t ws_size,
                              hipStream_t stream) {
  (void)in_sizes; (void)n_in; (void)out_size;
  const float* x     = (const float*)d_in[0];
  const float* adj1  = (const float*)d_in[1];
  const float* adj2  = (const float*)d_in[2];
  const float* valid = (const float*)d_in[3];
  const float* Wemb  = (const float*)d_in[4];
  const float* Wh    = (const float*)d_in[5];
  const float* bh    = (const float*)d_in[6];
  const float* We    = (const float*)d_in[7];
  const float* Wb    = (const float*)d_in[8];
  const float* bb    = (const float*)d_in[9];
  const float* Wfc0  = (const float*)d_in[10];
  const float* bfc0  = (const float*)d_in[11];
  const float* Wfcm  = (const float*)d_in[12];
  const float* bfcm  = (const float*)d_in[13];
  const float* Wfcl  = (const float*)d_in[14];
  const float* bfcl  = (const float*)d_in[15];
  float* out = (float*)d_out;

  // ---- workspace (fp32-element offsets) ----
  float* w = (float*)d_ws;
  size_t off = 0;
  float* c    = w + off; off += (size_t)BB * NN * DD;
  float* c1   = w + off; off += (size_t)BB * NN * DD;
  float* beta = w + off; off += (size_t)BB * NN * HH;
  float2* stats = (float2*)(w + off); off += (size_t)BB * HH * NN * 2;
  float* hWb  = w + off; off += (size_t)BB * NN * HH;
  unsigned short* c_bf = (unsigned short*)(w + off); off += (size_t)BB * NN * DD / 2;
  unsigned short* h_bf = (unsigned short*)(w + off); off += (size_t)BB * NN * HH * DD / 2;
  unsigned short* g_bf = (unsigned short*)(w + off); off += (size_t)BB * NN * HH * DD / 2;
  unsigned short* zA   = (unsigned short*)(w + off); off += (size_t)BB * NN * HH * DD / 2;
  unsigned short* zB   = (unsigned short*)(w + off); off += (size_t)BB * NN * HH * DD / 2;
  unsigned short* hT   = (unsigned short*)(w + off); off += (size_t)BB * HH * DD * NN / 2;
  unsigned short* zTA  = (unsigned short*)(w + off); off += (size_t)BB * HH * DD * NN / 2;
  unsigned short* zTB  = (unsigned short*)(w + off); off += (size_t)BB * HH * DD * NN / 2;
  unsigned short* WhT  = (unsigned short*)(w + off); off += (size_t)LL * 512 * 128 / 2;
  unsigned short* WeT  = (unsigned short*)(w + off); off += (size_t)LL * 128 * 128 / 2;
  unsigned int* maskT1 = (unsigned int*)(w + off); off += (size_t)BB * NN * 32;
  unsigned int* maskT2 = (unsigned int*)(w + off); off += (size_t)BB * NN * 32;
  const size_t fixedF = off;
  const size_t adjbfF = (size_t)BB * NN * NN / 2; // bf16 adj buffer, in floats
  const size_t eF = (size_t)HH * NN * NN / 2;     // per-batch e group, in floats
  const size_t wsF = ws_size / sizeof(float);

  int G = 8;
  bool useAdjbf = true;
  while (G > 1 && fixedF + 2 * adjbfF + (size_t)G * eF > wsF) G >>= 1;
  if (fixedF + 2 * adjbfF + (size_t)G * eF > wsF) {
    useAdjbf = false;
    G = 8;
    while (G > 1 && fixedF + (size_t)G * eF > wsF) G >>= 1;
  }
  const size_t base2 = fixedF + (useAdjbf ? 2 * adjbfF : 0);
  const bool eOnce = (base2 + 2ull * G * eF <= wsF);

  unsigned short* adjbf1 = useAdjbf ? (unsigned short*)(w + fixedF) : nullptr;
  unsigned short* adjbf2 = useAdjbf ? adjbf1 + (size_t)BB * NN * NN : nullptr;
  unsigned short* e = (unsigned short*)(w + base2);
  unsigned short* attB = eOnce ? (unsigned short*)(w + base2 + (size_t)G * eF) : e;

  k_maskT<<<dim3(32, 32, BB), 256, 0, stream>>>(adj1, maskT1);
  k_maskT<<<dim3(32, 32, BB), 256, 0, stream>>>(adj2, maskT2);
  if (useAdjbf) {
    k_copy_bf16<<<BB * NN * NN / 1024, 256, 0, stream>>>(adj1, adjbf1);
    k_copy_bf16<<<BB * NN * NN / 1024, 256, 0, stream>>>(adj2, adjbf2);
  }
  k_wtrans<<<dim3(4, 16, LL), 256, 0, stream>>>(Wh, WhT, 512);
  k_wtrans<<<dim3(4, 4, LL), 256, 0, stream>>>(We, WeT, 128);
  k_gemm_k128<<<dim3(128, 2), 256, 0, stream>>>(x, Wemb, c, c_bf, BB * NN, DD);

  for (int k = 0; k < LL; ++k) {
    k_gemm_nt<<<dim3(128, 8), 256, 0, stream>>>(
        c_bf, WhT + (size_t)k * 512 * 128, bh + (size_t)k * 512, h_bf, hT, 512);
    k_gemm_nt<<<dim3(512, 2), 256, 0, stream>>>(
        h_bf, WeT + (size_t)k * 128 * 128, nullptr, g_bf, nullptr, 128);
    k_hwb<<<BB * NN * HH / 4, 256, 0, stream>>>(h_bf, Wb + (size_t)k * 2 * DD, hWb);
    for (int b0 = 0; b0 < BB; b0 += G) {
      if (eOnce) k_e_st<<<dim3(16, 16, G * HH), 256, 0, stream>>>(g_bf, h_bf, e, b0);
      for (int br = 0; br < 2; ++br) {
        const float* adjcur = (br == 0) ? adj1 : adj2;
        const unsigned short* adjbfcur = useAdjbf ? ((br == 0) ? adjbf1 : adjbf2) : nullptr;
        const unsigned int* maskcur = (br == 0) ? maskT1 : maskT2;
        if (!eOnce) k_e_st<<<dim3(16, 16, G * HH), 256, 0, stream>>>(g_bf, h_bf, e, b0);
        k_stats<<<G * HH * NN, 128, 0, stream>>>(e, maskcur, stats, b0);
        k_attw<<<G * 2048, 256, 0, stream>>>(e, attB, adjbfcur, adjcur, stats, b0);
        // az0 fused: relu + beta + mix -> zA (and zTA when hops follow)
        k_az3<0><<<dim3(16, G * HH), 256, 0, stream>>>(
            attB, hT, h_bf, hWb, Wb + (size_t)k * 2 * DD, bb + k, beta,
            zA, (k >= 1) ? zTA : nullptr, b0);
        unsigned short *cur = zA, *curT = zTA, *nxt = zB, *nxtT = zTB;
        for (int t = 2; t <= k + 1; ++t) {
          k_az3<1><<<dim3(16, G * HH), 256, 0, stream>>>(
              attB, curT, h_bf, nullptr, nullptr, nullptr, beta,
              nxt, (t < k + 1) ? nxtT : nullptr, b0);
          unsigned short* tm1 = cur; cur = nxt; nxt = tm1;
          unsigned short* tm2 = curT; curT = nxtT; nxtT = tm2;
        }
        const size_t oH = (size_t)b0 * NN * 512;
        const size_t oC = (size_t)b0 * NN * DD;
        k_headmean<<<G * 512, 256, 0, stream>>>(
            cur + oH, (br == 0) ? nullptr : (c1 + oC), ((br == 0) ? c1 : c) + oC,
            (br == 0) ? nullptr : (c_bf + oC));
      }
    }
  }
  k_final<<<BB, 128, 0, stream>>>(c, valid, Wfc0, bfc0, Wfcm, bfcm, Wfcl, bfcl, out);
}

// Round 7
// 1378.824 us; speedup vs baseline: 2.6139x; 1.0285x over previous
//
#include <hip/hip_runtime.h>
#include <hip/hip_bf16.h>

#define BB 8
#define NN 1024
#define DD 128
#define HH 4
#define LL 4

typedef __attribute__((ext_vector_type(8))) short bf16x8;
typedef __attribute__((ext_vector_type(4))) float f32x4;
typedef __attribute__((ext_vector_type(8))) unsigned short u16x8;

__device__ __forceinline__ unsigned short f2bf(float f) {
  union { float f; unsigned int u; } v; v.f = f;
  unsigned int u = v.u;
  return (unsigned short)((u + 0x7FFFu + ((u >> 16) & 1u)) >> 16);
}
__device__ __forceinline__ float bf2f(unsigned short s) {
  union { unsigned int u; float f; } v; v.u = ((unsigned int)s) << 16;
  return v.f;
}
__device__ __forceinline__ unsigned short f2h(float f) {
  union { _Float16 h; unsigned short u; } v; v.h = (_Float16)f;
  return v.u;
}
__device__ __forceinline__ float h2f(unsigned short u) {
  union { unsigned short u; _Float16 h; } v; v.u = u;
  return (float)v.h;
}

// ------- maskT bits: maskW[b][r][word w] bit t = (adj[b][p=32w+t][r] > 0) ------
__global__ __launch_bounds__(256) void k_maskT(const float* __restrict__ in,
                                               unsigned int* __restrict__ maskW) {
  __shared__ float t[32][33];
  int b = blockIdx.z;
  int x0 = blockIdx.x * 32, y0 = blockIdx.y * 32;
  int tx = threadIdx.x & 31, ty = threadIdx.x >> 5;
  const float* ib = in + (size_t)b * NN * NN;
#pragma unroll
  for (int j = 0; j < 32; j += 8)
    t[ty + j][tx] = ib[(size_t)(y0 + ty + j) * NN + x0 + tx];
  __syncthreads();
  const int half = (threadIdx.x >> 5) & 1;
#pragma unroll
  for (int j = 0; j < 32; j += 8) {
    bool nz = t[tx][ty + j] > 0.f;
    unsigned long long bl = __ballot(nz);
    unsigned int word = half ? (unsigned int)(bl >> 32) : (unsigned int)bl;
    if (tx == 0)
      maskW[((size_t)b * NN + x0 + ty + j) * 32 + (y0 >> 5)] = word;
  }
}

// ------- compact adj rows: colidx/adjv slots (stride 128) + cnt per row --------
__global__ __launch_bounds__(256) void k_build(const float* __restrict__ adj,
                                               unsigned short* __restrict__ colidx,
                                               unsigned short* __restrict__ adjv,
                                               unsigned short* __restrict__ cnt) {
  const int b = blockIdx.y;
  const int wv = threadIdx.x >> 6, lane = threadIdx.x & 63;
  const int p = blockIdx.x * 4 + wv;
  const float* arow = adj + ((size_t)b * NN + p) * NN;
  const size_t base = ((size_t)b * NN + p) * 128;
  int run = 0;
  const unsigned long long lml = (lane == 63) ? 0x7FFFFFFFFFFFFFFFull
                                              : ((1ull << lane) - 1ull);
#pragma unroll
  for (int it = 0; it < 16; ++it) {
    float v = arow[it * 64 + lane];
    bool nz = v > 0.f;
    unsigned long long m = __ballot(nz);
    int pre = __popcll(m & lml);
    int slot = run + pre;
    if (nz && slot < 128) {
      colidx[base + slot] = (unsigned short)(it * 64 + lane);
      adjv[base + slot] = f2bf(v);
    }
    run += __popcll(m);
  }
  if (lane == 0) cnt[(size_t)b * NN + p] = (unsigned short)(run > 128 ? 128 : run);
}

// ------- weight transpose: in [nm][128][Nn] fp32 -> out [nm][Nn][128] bf16 -----
__global__ __launch_bounds__(256) void k_wtrans(const float* __restrict__ in,
                                                unsigned short* __restrict__ out, int Nn) {
  __shared__ float t[32][33];
  int m = blockIdx.z;
  const float* ib = in + (size_t)m * 128 * Nn;
  unsigned short* ob = out + (size_t)m * Nn * 128;
  int k0 = blockIdx.x * 32, n0 = blockIdx.y * 32;
  int tx = threadIdx.x & 31, ty = threadIdx.x >> 5;
#pragma unroll
  for (int j = 0; j < 32; j += 8)
    t[ty + j][tx] = ib[(size_t)(k0 + ty + j) * Nn + n0 + tx];
  __syncthreads();
#pragma unroll
  for (int j = 0; j < 32; j += 8)
    ob[(size_t)(n0 + ty + j) * 128 + k0 + tx] = f2bf(t[tx][ty + j]);
}

// ------- SIMT K=128 GEMM (embed only): C = A[M,128] @ Bw[128,Nn]; fp32+bf16 ----
__global__ __launch_bounds__(256) void k_gemm_k128(const float* __restrict__ A,
                                                   const float* __restrict__ Bw,
                                                   float* __restrict__ C,
                                                   unsigned short* __restrict__ Cbf,
                                                   int M, int Nn) {
  __shared__ __align__(16) float As[32][68];
  __shared__ __align__(16) float Bs[32][68];
  const int tm = blockIdx.x * 64, tn = blockIdx.y * 64;
  const int tid = threadIdx.x;
  const int ty = tid >> 4, tx = tid & 15;
  float acc[4][4] = {};
  for (int kc = 0; kc < 128; kc += 32) {
#pragma unroll
    for (int e = 0; e < 8; ++e) {
      int fl = tid + e * 256;
      int r = fl >> 5, k = fl & 31;
      As[k][r] = A[(size_t)(tm + r) * 128 + kc + k];
    }
#pragma unroll
    for (int e = 0; e < 8; ++e) {
      int fl = tid + e * 256;
      int k = fl >> 6, n = fl & 63;
      Bs[k][n] = Bw[(size_t)(kc + k) * Nn + tn + n];
    }
    __syncthreads();
#pragma unroll
    for (int kk = 0; kk < 32; ++kk) {
      float a4[4], b4[4];
      *(float4*)a4 = *(const float4*)&As[kk][ty * 4];
      *(float4*)b4 = *(const float4*)&Bs[kk][tx * 4];
#pragma unroll
      for (int i = 0; i < 4; ++i)
#pragma unroll
        for (int j = 0; j < 4; ++j) acc[i][j] += a4[i] * b4[j];
    }
    __syncthreads();
  }
#pragma unroll
  for (int i = 0; i < 4; ++i) {
    size_t base = (size_t)(tm + ty * 4 + i) * Nn + tn + tx * 4;
    *(float4*)&C[base] = *(float4*)acc[i];
    uint2 pv;
    pv.x = (unsigned int)f2bf(acc[i][0]) | ((unsigned int)f2bf(acc[i][1]) << 16);
    pv.y = (unsigned int)f2bf(acc[i][2]) | ((unsigned int)f2bf(acc[i][3]) << 16);
    *(uint2*)&Cbf[base] = pv;
  }
}

// ------- MFMA NT GEMM, K=128: out[M,Nn](bf16) = A[M,128](bf16) @ Bt[Nn,128]^T --
__global__ __launch_bounds__(256) void k_gemm_nt(const unsigned short* __restrict__ A,
                                                 const unsigned short* __restrict__ Bt,
                                                 const float* __restrict__ bias,
                                                 unsigned short* __restrict__ outp,
                                                 int Nn) {
  const int m0 = blockIdx.x * 64, n0 = blockIdx.y * 64;
  const int tid = threadIdx.x;
  const int wave = tid >> 6, lane = tid & 63;
  const int l15 = lane & 15, kq = lane >> 4;
  __shared__ __align__(16) unsigned short O[64][72];
  const unsigned short* aP = A + (size_t)(m0 + wave * 16 + l15) * 128;
  f32x4 acc[4] = {};
#pragma unroll
  for (int kk = 0; kk < 4; ++kk) {
    bf16x8 aF = *(const bf16x8*)(aP + (kk * 4 + kq) * 8);
#pragma unroll
    for (int cb = 0; cb < 4; ++cb) {
      bf16x8 bF = *(const bf16x8*)(Bt + (size_t)(n0 + cb * 16 + l15) * 128 + (kk * 4 + kq) * 8);
      acc[cb] = __builtin_amdgcn_mfma_f32_16x16x32_bf16(aF, bF, acc[cb], 0, 0, 0);
    }
  }
#pragma unroll
  for (int cb = 0; cb < 4; ++cb) {
    float bv = bias ? bias[n0 + cb * 16 + l15] : 0.f;
#pragma unroll
    for (int rg = 0; rg < 4; ++rg)
      O[wave * 16 + kq * 4 + rg][cb * 16 + l15] = f2bf(acc[cb][rg] + bv);
  }
  __syncthreads();
#pragma unroll
  for (int it = 0; it < 2; ++it) {
    int row = (tid >> 3) + it * 32, ch = tid & 7;
    *(uint4*)&outp[(size_t)(m0 + row) * Nn + n0 + ch * 8] = *(uint4*)&O[row][ch * 8];
  }
}

// ------- E tile via MFMA -> fp16 [p][r]: e = g[p]·h[r] + h[p]·g[r] (symmetric) -
__global__ __launch_bounds__(256) void k_e_st(const unsigned short* __restrict__ g,
                                              const unsigned short* __restrict__ h,
                                              unsigned short* __restrict__ e, int b0) {
  const int tp = blockIdx.x, tr = blockIdx.y;
  if (tp > tr) return;
  const int gi = blockIdx.z;
  const int b = b0 + (gi >> 2), i = gi & 3;
  const int p0 = tp * 64, r0 = tr * 64;
  const bool diag = (tp == tr);
  __shared__ __align__(16) char lds[32768];
  const int tid = threadIdx.x;
  const unsigned short* gb = g + (size_t)b * NN * 512 + i * 128;
  const unsigned short* hb = h + (size_t)b * NN * 512 + i * 128;
#pragma unroll
  for (int e2 = 0; e2 < 8; ++e2) {
    int fl = tid + e2 * 256;
    int t = fl >> 10, rem = fl & 1023;
    int row = rem >> 4, ch = rem & 15;
    const unsigned short* src = t ? hb : gb;
    uint4 v = *(const uint4*)(src + (size_t)(r0 + row) * 512 + ch * 8);
    *(uint4*)(lds + t * 16384 + row * 256 + ((ch ^ (row & 7)) * 16)) = v;
  }
  __syncthreads();
  const int wave = tid >> 6, lane = tid & 63;
  const int l15 = lane & 15, kq = lane >> 4;
  const unsigned short* aG = gb + (size_t)(p0 + wave * 16 + l15) * 512;
  const unsigned short* aH = hb + (size_t)(p0 + wave * 16 + l15) * 512;
  f32x4 acc[4] = {};
#pragma unroll
  for (int kk = 0; kk < 4; ++kk) {
    bf16x8 gA = *(const bf16x8*)(aG + (kk * 4 + kq) * 8);
    bf16x8 hA = *(const bf16x8*)(aH + (kk * 4 + kq) * 8);
#pragma unroll
    for (int cb = 0; cb < 4; ++cb) {
      int row = cb * 16 + l15;
      int chs = ((kk * 4 + kq) ^ (row & 7)) * 16;
      bf16x8 gB = *(const bf16x8*)(lds + row * 256 + chs);
      bf16x8 hB = *(const bf16x8*)(lds + 16384 + row * 256 + chs);
      acc[cb] = __builtin_amdgcn_mfma_f32_16x16x32_bf16(gA, hB, acc[cb], 0, 0, 0);
      acc[cb] = __builtin_amdgcn_mfma_f32_16x16x32_bf16(hA, gB, acc[cb], 0, 0, 0);
    }
  }
  __syncthreads();
  unsigned short* eN = (unsigned short*)lds;   // [64][72] fp16
  unsigned short* eT = eN + 64 * 72;
#pragma unroll
  for (int cb = 0; cb < 4; ++cb)
#pragma unroll
    for (int rg = 0; rg < 4; ++rg) {
      const int pl = wave * 16 + kq * 4 + rg, rl = cb * 16 + l15;
      const unsigned short v = f2h(acc[cb][rg]);
      eN[pl * 72 + rl] = v;
      if (!diag) eT[rl * 72 + pl] = v;
    }
  __syncthreads();
  unsigned short* eb = e + (size_t)gi * NN * NN;
#pragma unroll
  for (int it = 0; it < 2; ++it) {
    const int row = (tid >> 3) + it * 32, ch = tid & 7;
    *(uint4*)&eb[(size_t)(p0 + row) * NN + r0 + ch * 8] = *(uint4*)&eN[row * 72 + ch * 8];
    if (!diag)
      *(uint4*)&eb[(size_t)(r0 + row) * NN + p0 + ch * 8] = *(uint4*)&eT[row * 72 + ch * 8];
  }
}

// ------- per-column softmax stats via maskT bits: mx[r], inv[r] ----------------
__global__ __launch_bounds__(128) void k_stats(const unsigned short* __restrict__ e,
                                               const unsigned int* __restrict__ maskW,
                                               float2* __restrict__ stats, int b0) {
  const int col = blockIdx.x; // gi*N + r
  const int r = col & (NN - 1);
  const int gi = col >> 10;
  const int b = b0 + (gi >> 2);
  const unsigned short* erow = e + (size_t)col * NN;
  const int tid = threadIdx.x;
  u16x8 ev = *(const u16x8*)(erow + tid * 8);
  unsigned int word = maskW[((size_t)b * NN + r) * 32 + (tid >> 2)];
  unsigned int byte = (word >> ((tid & 3) * 8)) & 0xffu;
  float s[8];
#pragma unroll
  for (int j = 0; j < 8; ++j)
    s[j] = ((byte >> j) & 1u) ? h2f((unsigned short)ev[j]) : 0.f;
  float mx = s[0];
#pragma unroll
  for (int j = 1; j < 8; ++j) mx = fmaxf(mx, s[j]);
#pragma unroll
  for (int o = 32; o; o >>= 1) mx = fmaxf(mx, __shfl_xor(mx, o));
  __shared__ float sm[2], ss[2];
  const int wv = tid >> 6, ln = tid & 63;
  if (ln == 0) sm[wv] = mx;
  __syncthreads();
  mx = fmaxf(sm[0], sm[1]);
  float ps = 0.f;
#pragma unroll
  for (int j = 0; j < 8; ++j) ps += __expf(s[j] - mx); // masked -> exp(0-mx)
#pragma unroll
  for (int o = 32; o; o >>= 1) ps += __shfl_xor(ps, o);
  if (ln == 0) ss[wv] = ps;
  __syncthreads();
  if (tid == 0) stats[col] = make_float2(mx, 1.f / (ss[0] + ss[1]));
}

// ------- sparse attw: attP[gi][p][s] = (r<<16) | bf16(exp(E-mx)*inv*adjv) ------
__global__ __launch_bounds__(256) void k_attw_sp(const unsigned short* __restrict__ e,
                                                 const unsigned short* __restrict__ colidx,
                                                 const unsigned short* __restrict__ adjv,
                                                 const unsigned short* __restrict__ cnt,
                                                 const float2* __restrict__ stats,
                                                 unsigned int* __restrict__ attP, int b0) {
  const int gi = blockIdx.y;
  const int b = b0 + (gi >> 2);
  const int wv = threadIdx.x >> 6, lane = threadIdx.x & 63;
  const int p = blockIdx.x * 4 + wv;
  const int n = cnt[(size_t)b * NN + p];
  const int npad = (n + 7) & ~7;
  const size_t cbase = ((size_t)b * NN + p) * 128;
  const unsigned short* erow = e + ((size_t)gi * NN + p) * NN;
  const float2* st = stats + ((size_t)gi << 10);
  unsigned int* ob = attP + ((size_t)gi * NN + p) * 128;
  for (int s = lane; s < npad; s += 64) {
    unsigned int o = 0;
    if (s < n) {
      int r = colidx[cbase + s];
      float2 mi = st[r];
      float val = __expf(h2f(erow[r]) - mi.x) * mi.y * bf2f(adjv[cbase + s]);
      o = ((unsigned int)r << 16) | (unsigned int)f2bf(val);
    }
    ob[s] = o;
  }
}

// ---- hWb[(b*N+n)*H+i] = sum_d h[...,d] * Wb_k[d] ------------------------------
__global__ __launch_bounds__(256) void k_hwb(const unsigned short* __restrict__ h,
                                             const float* __restrict__ Wbk,
                                             float* __restrict__ hWb) {
  const int wid = threadIdx.x >> 6, lane = threadIdx.x & 63;
  const int idx = blockIdx.x * 4 + wid;
  const unsigned short* hp = h + (size_t)idx * 128;
  float s = 0.f;
#pragma unroll
  for (int e = 0; e < 2; ++e) {
    int d = lane + e * 64;
    s += bf2f(hp[d]) * Wbk[d];
  }
#pragma unroll
  for (int o = 32; o; o >>= 1) s += __shfl_xor(s, o);
  if (lane == 0) hWb[idx] = s;
}

// ---- sparse az + fused mix: one wave per output row p -------------------------
// az[d] = sum_s attv * z[r_s][d]; relu; MODE0: beta in-kernel; z = bt*h+(1-bt)*az
template <int MODE>
__global__ __launch_bounds__(256) void k_az_sp(const unsigned int* __restrict__ attP,
                                               const unsigned short* __restrict__ cnt,
                                               const unsigned short* __restrict__ zin,
                                               const unsigned short* __restrict__ h,
                                               const float* __restrict__ hWb,
                                               const float* __restrict__ Wbk,
                                               const float* __restrict__ bbk,
                                               float* __restrict__ betaBuf,
                                               unsigned short* __restrict__ outN, int b0) {
  const int gi = blockIdx.y;
  const int b = b0 + (gi >> 2), i = gi & 3;
  const int wv = threadIdx.x >> 6, lane = threadIdx.x & 63;
  const int p = blockIdx.x * 4 + wv;
  const int n = cnt[(size_t)b * NN + p];
  const int npad = (n + 7) & ~7;
  const unsigned int* ap = attP + ((size_t)gi * NN + p) * 128;
  const unsigned short* zb = zin + (size_t)b * NN * 512 + i * 128 + lane * 2;
  float a0 = 0.f, a1 = 0.f;
  for (int s = 0; s < npad; s += 8) {
    uint4 pa = *(const uint4*)(ap + s);
    uint4 pb = *(const uint4*)(ap + s + 4);
    unsigned int z0 = *(const unsigned int*)(zb + (size_t)(pa.x >> 16) * 512);
    unsigned int z1 = *(const unsigned int*)(zb + (size_t)(pa.y >> 16) * 512);
    unsigned int z2 = *(const unsigned int*)(zb + (size_t)(pa.z >> 16) * 512);
    unsigned int z3 = *(const unsigned int*)(zb + (size_t)(pa.w >> 16) * 512);
    unsigned int z4 = *(const unsigned int*)(zb + (size_t)(pb.x >> 16) * 512);
    unsigned int z5 = *(const unsigned int*)(zb + (size_t)(pb.y >> 16) * 512);
    unsigned int z6 = *(const unsigned int*)(zb + (size_t)(pb.z >> 16) * 512);
    unsigned int z7 = *(const unsigned int*)(zb + (size_t)(pb.w >> 16) * 512);
    float v0 = bf2f((unsigned short)(pa.x & 0xffff));
    float v1 = bf2f((unsigned short)(pa.y & 0xffff));
    float v2 = bf2f((unsigned short)(pa.z & 0xffff));
    float v3 = bf2f((unsigned short)(pa.w & 0xffff));
    float v4 = bf2f((unsigned short)(pb.x & 0xffff));
    float v5 = bf2f((unsigned short)(pb.y & 0xffff));
    float v6 = bf2f((unsigned short)(pb.z & 0xffff));
    float v7 = bf2f((unsigned short)(pb.w & 0xffff));
    a0 += v0 * bf2f((unsigned short)(z0 & 0xffff));
    a1 += v0 * bf2f((unsigned short)(z0 >> 16));
    a0 += v1 * bf2f((unsigned short)(z1 & 0xffff));
    a1 += v1 * bf2f((unsigned short)(z1 >> 16));
    a0 += v2 * bf2f((unsigned short)(z2 & 0xffff));
    a1 += v2 * bf2f((unsigned short)(z2 >> 16));
    a0 += v3 * bf2f((unsigned short)(z3 & 0xffff));
    a1 += v3 * bf2f((unsigned short)(z3 >> 16));
    a0 += v4 * bf2f((unsigned short)(z4 & 0xffff));
    a1 += v4 * bf2f((unsigned short)(z4 >> 16));
    a0 += v5 * bf2f((unsigned short)(z5 & 0xffff));
    a1 += v5 * bf2f((unsigned short)(z5 >> 16));
    a0 += v6 * bf2f((unsigned short)(z6 & 0xffff));
    a1 += v6 * bf2f((unsigned short)(z6 >> 16));
    a0 += v7 * bf2f((unsigned short)(z7 & 0xffff));
    a1 += v7 * bf2f((unsigned short)(z7 >> 16));
  }
  a0 = fmaxf(a0, 0.f);
  a1 = fmaxf(a1, 0.f);
  const size_t gidx = ((size_t)b * NN + p) * HH + i;
  float bt;
  if (MODE == 0) {
    float2 wb = *(const float2*)(Wbk + 128 + lane * 2);
    float part = a0 * wb.x + a1 * wb.y;
#pragma unroll
    for (int o = 32; o; o >>= 1) part += __shfl_xor(part, o);
    bt = 1.f / (1.f + __expf(-(hWb[gidx] + part + bbk[0])));
    if (lane == 0) betaBuf[gidx] = bt;
  } else {
    bt = betaBuf[gidx];
  }
  const float om = 1.f - bt;
  const size_t obase = (size_t)b * NN * 512 + (size_t)p * 512 + i * 128 + lane * 2;
  unsigned int hv = *(const unsigned int*)(h + obase);
  float z0o = bt * bf2f((unsigned short)(hv & 0xffff)) + om * a0;
  float z1o = bt * bf2f((unsigned short)(hv >> 16)) + om * a1;
  unsigned int zo = (unsigned int)f2bf(z0o) | ((unsigned int)f2bf(z1o) << 16);
  *(unsigned int*)(outN + obase) = zo;
}

// -------- out[n,d] = mean_i z[n,i,d] (- c1); c fp32 (+bf16); pre-offset --------
__global__ __launch_bounds__(256) void k_headmean(const unsigned short* __restrict__ z,
                                                  const float* __restrict__ c1,
                                                  float* __restrict__ outp,
                                                  unsigned short* __restrict__ outbf) {
  const int idx = blockIdx.x * 256 + threadIdx.x;
  const int d = idx & 127, bn = idx >> 7;
  const size_t base = (size_t)bn * 512 + d;
  float v = 0.25f * (bf2f(z[base]) + bf2f(z[base + 128]) +
                     bf2f(z[base + 256]) + bf2f(z[base + 384]));
  if (c1) v -= c1[idx];
  outp[idx] = v;
  if (outbf) outbf[idx] = f2bf(v);
}

// ---------------- node mean (parallel) + MLP head ------------------------------
__global__ __launch_bounds__(1024) void k_final2(const float* __restrict__ c,
                                                 const float* __restrict__ valid,
                                                 const float* __restrict__ Wfc0,
                                                 const float* __restrict__ bfc0,
                                                 const float* __restrict__ Wfcm,
                                                 const float* __restrict__ bfcm,
                                                 const float* __restrict__ Wfcl,
                                                 const float* __restrict__ bfcl,
                                                 float* __restrict__ out) {
  const int b = blockIdx.x, tid = threadIdx.x;
  const int ns = tid >> 7, d = tid & 127;
  __shared__ float red[8][128];
  __shared__ float vsh[8];
  __shared__ float bufA[128], bufB[128];
  float s = 0.f, vs = 0.f;
  const float* cb = c + ((size_t)b * NN + ns * 128) * 128 + d;
  const float* vb = valid + (size_t)b * NN + ns * 128;
  for (int n2 = 0; n2 < 128; ++n2) {
    float vv = vb[n2];
    s += cb[(size_t)n2 * 128] * vv;
    vs += vv;
  }
  red[ns][d] = s;
  if (d == 0) vsh[ns] = vs;
  __syncthreads();
  if (tid < 128) {
    float m = 0.f, vt = 0.f;
#pragma unroll
    for (int j = 0; j < 8; ++j) { m += red[j][tid]; vt += vsh[j]; }
    bufA[tid] = m / vt;
  }
  __syncthreads();
  if (tid < 128) {
    float t = bfc0[tid];
    for (int m = 0; m < 128; ++m) t += bufA[m] * Wfc0[m * 128 + tid];
    bufB[tid] = fmaxf(t, 0.f);
  }
  __syncthreads();
  if (tid < 128) {
    float t = bfcm[tid];
    for (int m = 0; m < 128; ++m) t += bufB[m] * Wfcm[m * 128 + tid];
    bufA[tid] = fmaxf(t, 0.f);
  }
  __syncthreads();
  if (tid < 128) {
    float t = bfcm[128 + tid];
    for (int m = 0; m < 128; ++m) t += bufA[m] * Wfcm[128 * 128 + m * 128 + tid];
    bufB[tid] = fmaxf(t, 0.f);
  }
  __syncthreads();
  if (tid < 128) red[0][tid] = bufB[tid] * Wfcl[tid];
  __syncthreads();
  if (tid < 64) red[0][tid] += red[0][tid + 64];
  __syncthreads();
  if (tid == 0) {
    float r = 0.f;
#pragma unroll
    for (int j = 0; j < 64; ++j) r += red[0][j];
    out[b] = 1.f / (1.f + __expf(-(r + bfcl[0])));
  }
}

extern "C" void kernel_launch(void* const* d_in, const int* in_sizes, int n_in,
                              void* d_out, int out_size, void* d_ws, size_t ws_size,
                              hipStream_t stream) {
  (void)in_sizes; (void)n_in; (void)out_size;
  const float* x     = (const float*)d_in[0];
  const float* adj1  = (const float*)d_in[1];
  const float* adj2  = (const float*)d_in[2];
  const float* valid = (const float*)d_in[3];
  const float* Wemb  = (const float*)d_in[4];
  const float* Wh    = (const float*)d_in[5];
  const float* bh    = (const float*)d_in[6];
  const float* We    = (const float*)d_in[7];
  const float* Wb    = (const float*)d_in[8];
  const float* bb    = (const float*)d_in[9];
  const float* Wfc0  = (const float*)d_in[10];
  const float* bfc0  = (const float*)d_in[11];
  const float* Wfcm  = (const float*)d_in[12];
  const float* bfcm  = (const float*)d_in[13];
  const float* Wfcl  = (const float*)d_in[14];
  const float* bfcl  = (const float*)d_in[15];
  float* out = (float*)d_out;

  // ---- workspace (fp32-element offsets) ----
  float* w = (float*)d_ws;
  size_t off = 0;
  float* c    = w + off; off += (size_t)BB * NN * DD;
  float* c1   = w + off; off += (size_t)BB * NN * DD;
  float* beta = w + off; off += (size_t)BB * NN * HH;
  float2* stats = (float2*)(w + off); off += (size_t)BB * HH * NN * 2;
  float* hWb  = w + off; off += (size_t)BB * NN * HH;
  unsigned short* c_bf = (unsigned short*)(w + off); off += (size_t)BB * NN * DD / 2;
  unsigned short* h_bf = (unsigned short*)(w + off); off += (size_t)BB * NN * HH * DD / 2;
  unsigned short* g_bf = (unsigned short*)(w + off); off += (size_t)BB * NN * HH * DD / 2;
  unsigned short* zA   = (unsigned short*)(w + off); off += (size_t)BB * NN * HH * DD / 2;
  unsigned short* zB   = (unsigned short*)(w + off); off += (size_t)BB * NN * HH * DD / 2;
  unsigned short* WhT  = (unsigned short*)(w + off); off += (size_t)LL * 512 * 128 / 2;
  unsigned short* WeT  = (unsigned short*)(w + off); off += (size_t)LL * 128 * 128 / 2;
  unsigned int* maskT1 = (unsigned int*)(w + off); off += (size_t)BB * NN * 32;
  unsigned int* maskT2 = (unsigned int*)(w + off); off += (size_t)BB * NN * 32;
  unsigned short* cidx1 = (unsigned short*)(w + off); off += (size_t)BB * NN * 128 / 2;
  unsigned short* cidx2 = (unsigned short*)(w + off); off += (size_t)BB * NN * 128 / 2;
  unsigned short* adjv1 = (unsigned short*)(w + off); off += (size_t)BB * NN * 128 / 2;
  unsigned short* adjv2 = (unsigned short*)(w + off); off += (size_t)BB * NN * 128 / 2;
  unsigned short* cnt1  = (unsigned short*)(w + off); off += (size_t)BB * NN / 2;
  unsigned short* cnt2  = (unsigned short*)(w + off); off += (size_t)BB * NN / 2;
  const size_t fixedF = off;
  const size_t eF = (size_t)HH * NN * NN / 2;     // per-batch fp16 E, in floats
  const size_t aF = (size_t)HH * NN * 128;        // per-batch packed attP, in floats
  const size_t wsF = ws_size / sizeof(float);

  int G = 8;
  while (G > 1 && fixedF + (size_t)G * (eF + aF) > wsF) G >>= 1;

  unsigned short* e = (unsigned short*)(w + fixedF);
  unsigned int* attP = (unsigned int*)(w + fixedF + (size_t)G * eF);

  k_maskT<<<dim3(32, 32, BB), 256, 0, stream>>>(adj1, maskT1);
  k_maskT<<<dim3(32, 32, BB), 256, 0, stream>>>(adj2, maskT2);
  k_build<<<dim3(256, BB), 256, 0, stream>>>(adj1, cidx1, adjv1, cnt1);
  k_build<<<dim3(256, BB), 256, 0, stream>>>(adj2, cidx2, adjv2, cnt2);
  k_wtrans<<<dim3(4, 16, LL), 256, 0, stream>>>(Wh, WhT, 512);
  k_wtrans<<<dim3(4, 4, LL), 256, 0, stream>>>(We, WeT, 128);
  k_gemm_k128<<<dim3(128, 2), 256, 0, stream>>>(x, Wemb, c, c_bf, BB * NN, DD);

  for (int k = 0; k < LL; ++k) {
    k_gemm_nt<<<dim3(128, 8), 256, 0, stream>>>(
        c_bf, WhT + (size_t)k * 512 * 128, bh + (size_t)k * 512, h_bf, 512);
    k_gemm_nt<<<dim3(512, 2), 256, 0, stream>>>(
        h_bf, WeT + (size_t)k * 128 * 128, nullptr, g_bf, 128);
    k_hwb<<<BB * NN * HH / 4, 256, 0, stream>>>(h_bf, Wb + (size_t)k * 2 * DD, hWb);
    for (int b0 = 0; b0 < BB; b0 += G) {
      k_e_st<<<dim3(16, 16, G * HH), 256, 0, stream>>>(g_bf, h_bf, e, b0);
      for (int br = 0; br < 2; ++br) {
        const unsigned int* maskcur = (br == 0) ? maskT1 : maskT2;
        const unsigned short* cidx = (br == 0) ? cidx1 : cidx2;
        const unsigned short* adjv = (br == 0) ? adjv1 : adjv2;
        const unsigned short* cnt = (br == 0) ? cnt1 : cnt2;
        k_stats<<<G * HH * NN, 128, 0, stream>>>(e, maskcur, stats, b0);
        k_attw_sp<<<dim3(256, G * HH), 256, 0, stream>>>(e, cidx, adjv, cnt, stats,
                                                         attP, b0);
        // az0 fused: relu + beta + mix -> zA (hop 1 uses z=h)
        k_az_sp<0><<<dim3(256, G * HH), 256, 0, stream>>>(
            attP, cnt, h_bf, h_bf, hWb, Wb + (size_t)k * 2 * DD, bb + k, beta, zA, b0);
        unsigned short *cur = zA, *nxt = zB;
        for (int t = 2; t <= k + 1; ++t) {
          k_az_sp<1><<<dim3(256, G * HH), 256, 0, stream>>>(
              attP, cnt, cur, h_bf, nullptr, nullptr, nullptr, beta, nxt, b0);
          unsigned short* tm1 = cur; cur = nxt; nxt = tm1;
        }
        const size_t oH = (size_t)b0 * NN * 512;
        const size_t oC = (size_t)b0 * NN * DD;
        k_headmean<<<G * 512, 256, 0, stream>>>(
            cur + oH, (br == 0) ? nullptr : (c1 + oC), ((br == 0) ? c1 : c) + oC,
            (br == 0) ? nullptr : (c_bf + oC));
      }
    }
  }
  k_final2<<<BB, 1024, 0, stream>>>(c, valid, Wfc0, bfc0, Wfcm, bfcm, Wfcl, bfcl, out);
}

// Round 8
// 1235.172 us; speedup vs baseline: 2.9179x; 1.1163x over previous
//
#include <hip/hip_runtime.h>
#include <hip/hip_bf16.h>

#define BB 8
#define NN 1024
#define DD 128
#define HH 4
#define LL 4

typedef __attribute__((ext_vector_type(8))) short bf16x8;
typedef __attribute__((ext_vector_type(4))) float f32x4;
typedef __attribute__((ext_vector_type(8))) unsigned short u16x8;

__device__ __forceinline__ unsigned short f2bf(float f) {
  union { float f; unsigned int u; } v; v.f = f;
  unsigned int u = v.u;
  return (unsigned short)((u + 0x7FFFu + ((u >> 16) & 1u)) >> 16);
}
__device__ __forceinline__ float bf2f(unsigned short s) {
  union { unsigned int u; float f; } v; v.u = ((unsigned int)s) << 16;
  return v.f;
}
__device__ __forceinline__ unsigned short f2h(float f) {
  union { _Float16 h; unsigned short u; } v; v.h = (_Float16)f;
  return v.u;
}
__device__ __forceinline__ float h2f(unsigned short u) {
  union { unsigned short u; _Float16 h; } v; v.u = u;
  return (float)v.h;
}

// ------- maskT bits: maskW[b][r][word w] bit t = (adj[b][p=32w+t][r] > 0) ------
__global__ __launch_bounds__(256) void k_maskT(const float* __restrict__ in,
                                               unsigned int* __restrict__ maskW) {
  __shared__ float t[32][33];
  int b = blockIdx.z;
  int x0 = blockIdx.x * 32, y0 = blockIdx.y * 32;
  int tx = threadIdx.x & 31, ty = threadIdx.x >> 5;
  const float* ib = in + (size_t)b * NN * NN;
#pragma unroll
  for (int j = 0; j < 32; j += 8)
    t[ty + j][tx] = ib[(size_t)(y0 + ty + j) * NN + x0 + tx];
  __syncthreads();
  const int half = (threadIdx.x >> 5) & 1;
#pragma unroll
  for (int j = 0; j < 32; j += 8) {
    bool nz = t[tx][ty + j] > 0.f;
    unsigned long long bl = __ballot(nz);
    unsigned int word = half ? (unsigned int)(bl >> 32) : (unsigned int)bl;
    if (tx == 0)
      maskW[((size_t)b * NN + x0 + ty + j) * 32 + (y0 >> 5)] = word;
  }
}

// ------- compact adj rows: colidx/adjv slots (stride 128) + cnt per row --------
__global__ __launch_bounds__(256) void k_build(const float* __restrict__ adj,
                                               unsigned short* __restrict__ colidx,
                                               unsigned short* __restrict__ adjv,
                                               unsigned short* __restrict__ cnt) {
  const int b = blockIdx.y;
  const int wv = threadIdx.x >> 6, lane = threadIdx.x & 63;
  const int p = blockIdx.x * 4 + wv;
  const float* arow = adj + ((size_t)b * NN + p) * NN;
  const size_t base = ((size_t)b * NN + p) * 128;
  int run = 0;
  const unsigned long long lml = (lane == 63) ? 0x7FFFFFFFFFFFFFFFull
                                              : ((1ull << lane) - 1ull);
#pragma unroll
  for (int it = 0; it < 16; ++it) {
    float v = arow[it * 64 + lane];
    bool nz = v > 0.f;
    unsigned long long m = __ballot(nz);
    int pre = __popcll(m & lml);
    int slot = run + pre;
    if (nz && slot < 128) {
      colidx[base + slot] = (unsigned short)(it * 64 + lane);
      adjv[base + slot] = f2bf(v);
    }
    run += __popcll(m);
  }
  if (lane == 0) cnt[(size_t)b * NN + p] = (unsigned short)(run > 128 ? 128 : run);
}

// ------- weight transpose: in [nm][128][Nn] fp32 -> out [nm][Nn][128] bf16 -----
__global__ __launch_bounds__(256) void k_wtrans(const float* __restrict__ in,
                                                unsigned short* __restrict__ out, int Nn) {
  __shared__ float t[32][33];
  int m = blockIdx.z;
  const float* ib = in + (size_t)m * 128 * Nn;
  unsigned short* ob = out + (size_t)m * Nn * 128;
  int k0 = blockIdx.x * 32, n0 = blockIdx.y * 32;
  int tx = threadIdx.x & 31, ty = threadIdx.x >> 5;
#pragma unroll
  for (int j = 0; j < 32; j += 8)
    t[ty + j][tx] = ib[(size_t)(k0 + ty + j) * Nn + n0 + tx];
  __syncthreads();
#pragma unroll
  for (int j = 0; j < 32; j += 8)
    ob[(size_t)(n0 + ty + j) * 128 + k0 + tx] = f2bf(t[tx][ty + j]);
}

// ------- SIMT K=128 GEMM (embed only): C = A[M,128] @ Bw[128,Nn]; fp32+bf16 ----
__global__ __launch_bounds__(256) void k_gemm_k128(const float* __restrict__ A,
                                                   const float* __restrict__ Bw,
                                                   float* __restrict__ C,
                                                   unsigned short* __restrict__ Cbf,
                                                   int M, int Nn) {
  __shared__ __align__(16) float As[32][68];
  __shared__ __align__(16) float Bs[32][68];
  const int tm = blockIdx.x * 64, tn = blockIdx.y * 64;
  const int tid = threadIdx.x;
  const int ty = tid >> 4, tx = tid & 15;
  float acc[4][4] = {};
  for (int kc = 0; kc < 128; kc += 32) {
#pragma unroll
    for (int e = 0; e < 8; ++e) {
      int fl = tid + e * 256;
      int r = fl >> 5, k = fl & 31;
      As[k][r] = A[(size_t)(tm + r) * 128 + kc + k];
    }
#pragma unroll
    for (int e = 0; e < 8; ++e) {
      int fl = tid + e * 256;
      int k = fl >> 6, n = fl & 63;
      Bs[k][n] = Bw[(size_t)(kc + k) * Nn + tn + n];
    }
    __syncthreads();
#pragma unroll
    for (int kk = 0; kk < 32; ++kk) {
      float a4[4], b4[4];
      *(float4*)a4 = *(const float4*)&As[kk][ty * 4];
      *(float4*)b4 = *(const float4*)&Bs[kk][tx * 4];
#pragma unroll
      for (int i = 0; i < 4; ++i)
#pragma unroll
        for (int j = 0; j < 4; ++j) acc[i][j] += a4[i] * b4[j];
    }
    __syncthreads();
  }
#pragma unroll
  for (int i = 0; i < 4; ++i) {
    size_t base = (size_t)(tm + ty * 4 + i) * Nn + tn + tx * 4;
    *(float4*)&C[base] = *(float4*)acc[i];
    uint2 pv;
    pv.x = (unsigned int)f2bf(acc[i][0]) | ((unsigned int)f2bf(acc[i][1]) << 16);
    pv.y = (unsigned int)f2bf(acc[i][2]) | ((unsigned int)f2bf(acc[i][3]) << 16);
    *(uint2*)&Cbf[base] = pv;
  }
}

// ------- MFMA NT GEMM, K=128: out[M,Nn](bf16) = A[M,128](bf16) @ Bt[Nn,128]^T --
__global__ __launch_bounds__(256) void k_gemm_nt(const unsigned short* __restrict__ A,
                                                 const unsigned short* __restrict__ Bt,
                                                 const float* __restrict__ bias,
                                                 unsigned short* __restrict__ outp,
                                                 int Nn) {
  const int m0 = blockIdx.x * 64, n0 = blockIdx.y * 64;
  const int tid = threadIdx.x;
  const int wave = tid >> 6, lane = tid & 63;
  const int l15 = lane & 15, kq = lane >> 4;
  __shared__ __align__(16) unsigned short O[64][72];
  const unsigned short* aP = A + (size_t)(m0 + wave * 16 + l15) * 128;
  f32x4 acc[4] = {};
#pragma unroll
  for (int kk = 0; kk < 4; ++kk) {
    bf16x8 aF = *(const bf16x8*)(aP + (kk * 4 + kq) * 8);
#pragma unroll
    for (int cb = 0; cb < 4; ++cb) {
      bf16x8 bF = *(const bf16x8*)(Bt + (size_t)(n0 + cb * 16 + l15) * 128 + (kk * 4 + kq) * 8);
      acc[cb] = __builtin_amdgcn_mfma_f32_16x16x32_bf16(aF, bF, acc[cb], 0, 0, 0);
    }
  }
#pragma unroll
  for (int cb = 0; cb < 4; ++cb) {
    float bv = bias ? bias[n0 + cb * 16 + l15] : 0.f;
#pragma unroll
    for (int rg = 0; rg < 4; ++rg)
      O[wave * 16 + kq * 4 + rg][cb * 16 + l15] = f2bf(acc[cb][rg] + bv);
  }
  __syncthreads();
#pragma unroll
  for (int it = 0; it < 2; ++it) {
    int row = (tid >> 3) + it * 32, ch = tid & 7;
    *(uint4*)&outp[(size_t)(m0 + row) * Nn + n0 + ch * 8] = *(uint4*)&O[row][ch * 8];
  }
}

// ------- E tile via MFMA -> fp16 [p][r]: triangular grid (136 live pairs) ------
__global__ __launch_bounds__(256) void k_e_st(const unsigned short* __restrict__ g,
                                              const unsigned short* __restrict__ h,
                                              unsigned short* __restrict__ e, int b0) {
  const int t0 = blockIdx.x; // 0..135 -> (tp <= tr)
  int tr = (int)((sqrtf(8.f * t0 + 1.f) - 1.f) * 0.5f);
  while ((tr + 1) * (tr + 2) / 2 <= t0) ++tr;
  while (tr * (tr + 1) / 2 > t0) --tr;
  const int tp = t0 - tr * (tr + 1) / 2;
  const int gi = blockIdx.y;
  const int b = b0 + (gi >> 2), i = gi & 3;
  const int p0 = tp * 64, r0 = tr * 64;
  const bool diag = (tp == tr);
  __shared__ __align__(16) char lds[32768];
  const int tid = threadIdx.x;
  const unsigned short* gb = g + (size_t)b * NN * 512 + i * 128;
  const unsigned short* hb = h + (size_t)b * NN * 512 + i * 128;
#pragma unroll
  for (int e2 = 0; e2 < 8; ++e2) {
    int fl = tid + e2 * 256;
    int t = fl >> 10, rem = fl & 1023;
    int row = rem >> 4, ch = rem & 15;
    const unsigned short* src = t ? hb : gb;
    uint4 v = *(const uint4*)(src + (size_t)(r0 + row) * 512 + ch * 8);
    *(uint4*)(lds + t * 16384 + row * 256 + ((ch ^ (row & 7)) * 16)) = v;
  }
  __syncthreads();
  const int wave = tid >> 6, lane = tid & 63;
  const int l15 = lane & 15, kq = lane >> 4;
  const unsigned short* aG = gb + (size_t)(p0 + wave * 16 + l15) * 512;
  const unsigned short* aH = hb + (size_t)(p0 + wave * 16 + l15) * 512;
  f32x4 acc[4] = {};
#pragma unroll
  for (int kk = 0; kk < 4; ++kk) {
    bf16x8 gA = *(const bf16x8*)(aG + (kk * 4 + kq) * 8);
    bf16x8 hA = *(const bf16x8*)(aH + (kk * 4 + kq) * 8);
#pragma unroll
    for (int cb = 0; cb < 4; ++cb) {
      int row = cb * 16 + l15;
      int chs = ((kk * 4 + kq) ^ (row & 7)) * 16;
      bf16x8 gB = *(const bf16x8*)(lds + row * 256 + chs);
      bf16x8 hB = *(const bf16x8*)(lds + 16384 + row * 256 + chs);
      acc[cb] = __builtin_amdgcn_mfma_f32_16x16x32_bf16(gA, hB, acc[cb], 0, 0, 0);
      acc[cb] = __builtin_amdgcn_mfma_f32_16x16x32_bf16(hA, gB, acc[cb], 0, 0, 0);
    }
  }
  __syncthreads();
  unsigned short* eN = (unsigned short*)lds;   // [64][72] fp16
  unsigned short* eT = eN + 64 * 72;
#pragma unroll
  for (int cb = 0; cb < 4; ++cb)
#pragma unroll
    for (int rg = 0; rg < 4; ++rg) {
      const int pl = wave * 16 + kq * 4 + rg, rl = cb * 16 + l15;
      const unsigned short v = f2h(acc[cb][rg]);
      eN[pl * 72 + rl] = v;
      if (!diag) eT[rl * 72 + pl] = v;
    }
  __syncthreads();
  unsigned short* eb = e + (size_t)gi * NN * NN;
#pragma unroll
  for (int it = 0; it < 2; ++it) {
    const int row = (tid >> 3) + it * 32, ch = tid & 7;
    *(uint4*)&eb[(size_t)(p0 + row) * NN + r0 + ch * 8] = *(uint4*)&eN[row * 72 + ch * 8];
    if (!diag)
      *(uint4*)&eb[(size_t)(r0 + row) * NN + p0 + ch * 8] = *(uint4*)&eT[row * 72 + ch * 8];
  }
}

// ------- both-branch stats from ONE E-row read: mx[r], inv[r] per branch -------
__global__ __launch_bounds__(128) void k_stats2(const unsigned short* __restrict__ e,
                                                const unsigned int* __restrict__ m1,
                                                const unsigned int* __restrict__ m2,
                                                float2* __restrict__ stats,
                                                size_t statsS, int b0) {
  const int col = blockIdx.x; // local gi*N + r
  const int r = col & (NN - 1);
  const int gi = col >> 10;
  const int b = b0 + (gi >> 2);
  const unsigned short* erow = e + (size_t)col * NN;
  const int tid = threadIdx.x;
  u16x8 ev = *(const u16x8*)(erow + tid * 8);
  float evf[8];
#pragma unroll
  for (int j = 0; j < 8; ++j) evf[j] = h2f((unsigned short)ev[j]);
  const size_t moff = ((size_t)b * NN + r) * 32 + (tid >> 2);
  const int sh = (tid & 3) * 8;
  unsigned int by1 = (m1[moff] >> sh) & 0xffu;
  unsigned int by2 = (m2[moff] >> sh) & 0xffu;
  float mx1 = 0.f, mx2 = 0.f; // masked entries contribute 0 -> max includes 0
#pragma unroll
  for (int j = 0; j < 8; ++j) {
    if ((by1 >> j) & 1u) mx1 = fmaxf(mx1, evf[j]);
    if ((by2 >> j) & 1u) mx2 = fmaxf(mx2, evf[j]);
  }
#pragma unroll
  for (int o = 32; o; o >>= 1) {
    mx1 = fmaxf(mx1, __shfl_xor(mx1, o));
    mx2 = fmaxf(mx2, __shfl_xor(mx2, o));
  }
  __shared__ float sm1[2], sm2[2], ss1[2], ss2[2];
  const int wv = tid >> 6, ln = tid & 63;
  if (ln == 0) { sm1[wv] = mx1; sm2[wv] = mx2; }
  __syncthreads();
  mx1 = fmaxf(sm1[0], sm1[1]);
  mx2 = fmaxf(sm2[0], sm2[1]);
  float ps1 = 0.f, ps2 = 0.f;
#pragma unroll
  for (int j = 0; j < 8; ++j) {
    float s1 = ((by1 >> j) & 1u) ? evf[j] : 0.f;
    float s2 = ((by2 >> j) & 1u) ? evf[j] : 0.f;
    ps1 += __expf(s1 - mx1);
    ps2 += __expf(s2 - mx2);
  }
#pragma unroll
  for (int o = 32; o; o >>= 1) {
    ps1 += __shfl_xor(ps1, o);
    ps2 += __shfl_xor(ps2, o);
  }
  if (ln == 0) { ss1[wv] = ps1; ss2[wv] = ps2; }
  __syncthreads();
  if (tid == 0) {
    const size_t gcol = (((size_t)gi + (size_t)b0 * HH) << 10) + r;
    stats[gcol] = make_float2(mx1, 1.f / (ss1[0] + ss1[1]));
    stats[statsS + gcol] = make_float2(mx2, 1.f / (ss2[0] + ss2[1]));
  }
}

// ------- sparse attw both branches: attP[br][gi][p][s] = (r<<16)|bf16(att) -----
__global__ __launch_bounds__(256) void k_attw2(const unsigned short* __restrict__ e,
                                               const unsigned short* __restrict__ cidxB,
                                               const unsigned short* __restrict__ adjvB,
                                               const unsigned short* __restrict__ cntB,
                                               size_t adjS, size_t cntS,
                                               const float2* __restrict__ stats,
                                               size_t statsS,
                                               unsigned int* __restrict__ attP,
                                               size_t attS, int b0) {
  const int br = blockIdx.z;
  const int gi = blockIdx.y;
  const int b = b0 + (gi >> 2);
  const unsigned short* cidx = cidxB + (size_t)br * adjS;
  const unsigned short* adjv = adjvB + (size_t)br * adjS;
  const int wv = threadIdx.x >> 6, lane = threadIdx.x & 63;
  const int p = blockIdx.x * 4 + wv;
  const int n = cntB[(size_t)br * cntS + (size_t)b * NN + p];
  const int npad = (n + 7) & ~7;
  const size_t cbase = ((size_t)b * NN + p) * 128;
  const unsigned short* erow = e + ((size_t)gi * NN + p) * NN;
  const float2* st = stats + (size_t)br * statsS + (((size_t)gi + (size_t)b0 * HH) << 10);
  unsigned int* ob = attP + (size_t)br * attS + ((size_t)gi * NN + p) * 128;
  for (int s = lane; s < npad; s += 64) {
    unsigned int o = 0;
    if (s < n) {
      int r = cidx[cbase + s];
      float2 mi = st[r];
      float val = __expf(h2f(erow[r]) - mi.x) * mi.y * bf2f(adjv[cbase + s]);
      o = ((unsigned int)r << 16) | (unsigned int)f2bf(val);
    }
    ob[s] = o;
  }
}

// ---- hWb[(b*N+n)*H+i] = sum_d h[...,d] * Wb_k[d] ------------------------------
__global__ __launch_bounds__(256) void k_hwb(const unsigned short* __restrict__ h,
                                             const float* __restrict__ Wbk,
                                             float* __restrict__ hWb) {
  const int wid = threadIdx.x >> 6, lane = threadIdx.x & 63;
  const int idx = blockIdx.x * 4 + wid;
  const unsigned short* hp = h + (size_t)idx * 128;
  float s = 0.f;
#pragma unroll
  for (int e = 0; e < 2; ++e) {
    int d = lane + e * 64;
    s += bf2f(hp[d]) * Wbk[d];
  }
#pragma unroll
  for (int o = 32; o; o >>= 1) s += __shfl_xor(s, o);
  if (lane == 0) hWb[idx] = s;
}

// ---- sparse az both branches + fused mix: one wave per output row p -----------
template <int MODE>
__global__ __launch_bounds__(256) void k_az2(const unsigned int* __restrict__ attP,
                                             size_t attS,
                                             const unsigned short* __restrict__ cntB,
                                             size_t cntS,
                                             const unsigned short* __restrict__ zin,
                                             size_t zinS,
                                             const unsigned short* __restrict__ h,
                                             const float* __restrict__ hWb,
                                             const float* __restrict__ Wbk,
                                             const float* __restrict__ bbk,
                                             float* __restrict__ betaB, size_t betaS,
                                             unsigned short* __restrict__ outB,
                                             size_t outS, int b0) {
  const int br = blockIdx.z;
  const int gi = blockIdx.y;
  const int b = b0 + (gi >> 2), i = gi & 3;
  const int wv = threadIdx.x >> 6, lane = threadIdx.x & 63;
  const int p = blockIdx.x * 4 + wv;
  const int n = cntB[(size_t)br * cntS + (size_t)b * NN + p];
  const int npad = (n + 7) & ~7;
  const unsigned int* ap = attP + (size_t)br * attS + ((size_t)gi * NN + p) * 128;
  const unsigned short* zb = zin + (size_t)br * zinS + (size_t)b * NN * 512 + i * 128 + lane * 2;
  float a0 = 0.f, a1 = 0.f;
  for (int s = 0; s < npad; s += 8) {
    uint4 pa = *(const uint4*)(ap + s);
    uint4 pb = *(const uint4*)(ap + s + 4);
    unsigned int z0 = *(const unsigned int*)(zb + (size_t)(pa.x >> 16) * 512);
    unsigned int z1 = *(const unsigned int*)(zb + (size_t)(pa.y >> 16) * 512);
    unsigned int z2 = *(const unsigned int*)(zb + (size_t)(pa.z >> 16) * 512);
    unsigned int z3 = *(const unsigned int*)(zb + (size_t)(pa.w >> 16) * 512);
    unsigned int z4 = *(const unsigned int*)(zb + (size_t)(pb.x >> 16) * 512);
    unsigned int z5 = *(const unsigned int*)(zb + (size_t)(pb.y >> 16) * 512);
    unsigned int z6 = *(const unsigned int*)(zb + (size_t)(pb.z >> 16) * 512);
    unsigned int z7 = *(const unsigned int*)(zb + (size_t)(pb.w >> 16) * 512);
    float v0 = bf2f((unsigned short)(pa.x & 0xffff));
    float v1 = bf2f((unsigned short)(pa.y & 0xffff));
    float v2 = bf2f((unsigned short)(pa.z & 0xffff));
    float v3 = bf2f((unsigned short)(pa.w & 0xffff));
    float v4 = bf2f((unsigned short)(pb.x & 0xffff));
    float v5 = bf2f((unsigned short)(pb.y & 0xffff));
    float v6 = bf2f((unsigned short)(pb.z & 0xffff));
    float v7 = bf2f((unsigned short)(pb.w & 0xffff));
    a0 += v0 * bf2f((unsigned short)(z0 & 0xffff));
    a1 += v0 * bf2f((unsigned short)(z0 >> 16));
    a0 += v1 * bf2f((unsigned short)(z1 & 0xffff));
    a1 += v1 * bf2f((unsigned short)(z1 >> 16));
    a0 += v2 * bf2f((unsigned short)(z2 & 0xffff));
    a1 += v2 * bf2f((unsigned short)(z2 >> 16));
    a0 += v3 * bf2f((unsigned short)(z3 & 0xffff));
    a1 += v3 * bf2f((unsigned short)(z3 >> 16));
    a0 += v4 * bf2f((unsigned short)(z4 & 0xffff));
    a1 += v4 * bf2f((unsigned short)(z4 >> 16));
    a0 += v5 * bf2f((unsigned short)(z5 & 0xffff));
    a1 += v5 * bf2f((unsigned short)(z5 >> 16));
    a0 += v6 * bf2f((unsigned short)(z6 & 0xffff));
    a1 += v6 * bf2f((unsigned short)(z6 >> 16));
    a0 += v7 * bf2f((unsigned short)(z7 & 0xffff));
    a1 += v7 * bf2f((unsigned short)(z7 >> 16));
  }
  a0 = fmaxf(a0, 0.f);
  a1 = fmaxf(a1, 0.f);
  const size_t gidx = ((size_t)b * NN + p) * HH + i;
  float bt;
  if (MODE == 0) {
    float2 wb = *(const float2*)(Wbk + 128 + lane * 2);
    float part = a0 * wb.x + a1 * wb.y;
#pragma unroll
    for (int o = 32; o; o >>= 1) part += __shfl_xor(part, o);
    bt = 1.f / (1.f + __expf(-(hWb[gidx] + part + bbk[0])));
    if (lane == 0) betaB[(size_t)br * betaS + gidx] = bt;
  } else {
    bt = betaB[(size_t)br * betaS + gidx];
  }
  const float om = 1.f - bt;
  const size_t obase = (size_t)b * NN * 512 + (size_t)p * 512 + i * 128 + lane * 2;
  unsigned int hv = *(const unsigned int*)(h + obase);
  float z0o = bt * bf2f((unsigned short)(hv & 0xffff)) + om * a0;
  float z1o = bt * bf2f((unsigned short)(hv >> 16)) + om * a1;
  unsigned int zo = (unsigned int)f2bf(z0o) | ((unsigned int)f2bf(z1o) << 16);
  *(unsigned int*)(outB + (size_t)br * outS + obase) = zo;
}

// ---- out[n,d] = mean_i z2[n,i,d] - mean_i z1[n,i,d]; c fp32 + bf16 ------------
__global__ __launch_bounds__(256) void k_headmean2(const unsigned short* __restrict__ z1,
                                                   const unsigned short* __restrict__ z2,
                                                   float* __restrict__ outp,
                                                   unsigned short* __restrict__ outbf) {
  const int idx = blockIdx.x * 256 + threadIdx.x;
  const int d = idx & 127, bn = idx >> 7;
  const size_t base = (size_t)bn * 512 + d;
  float v1 = bf2f(z1[base]) + bf2f(z1[base + 128]) + bf2f(z1[base + 256]) + bf2f(z1[base + 384]);
  float v2 = bf2f(z2[base]) + bf2f(z2[base + 128]) + bf2f(z2[base + 256]) + bf2f(z2[base + 384]);
  float v = 0.25f * (v2 - v1);
  outp[idx] = v;
  outbf[idx] = f2bf(v);
}

// ---------------- node mean (parallel) + MLP head ------------------------------
__global__ __launch_bounds__(1024) void k_final2(const float* __restrict__ c,
                                                 const float* __restrict__ valid,
                                                 const float* __restrict__ Wfc0,
                                                 const float* __restrict__ bfc0,
                                                 const float* __restrict__ Wfcm,
                                                 const float* __restrict__ bfcm,
                                                 const float* __restrict__ Wfcl,
                                                 const float* __restrict__ bfcl,
                                                 float* __restrict__ out) {
  const int b = blockIdx.x, tid = threadIdx.x;
  const int ns = tid >> 7, d = tid & 127;
  __shared__ float red[8][128];
  __shared__ float vsh[8];
  __shared__ float bufA[128], bufB[128];
  float s = 0.f, vs = 0.f;
  const float* cb = c + ((size_t)b * NN + ns * 128) * 128 + d;
  const float* vb = valid + (size_t)b * NN + ns * 128;
  for (int n2 = 0; n2 < 128; ++n2) {
    float vv = vb[n2];
    s += cb[(size_t)n2 * 128] * vv;
    vs += vv;
  }
  red[ns][d] = s;
  if (d == 0) vsh[ns] = vs;
  __syncthreads();
  if (tid < 128) {
    float m = 0.f, vt = 0.f;
#pragma unroll
    for (int j = 0; j < 8; ++j) { m += red[j][tid]; vt += vsh[j]; }
    bufA[tid] = m / vt;
  }
  __syncthreads();
  if (tid < 128) {
    float t = bfc0[tid];
    for (int m = 0; m < 128; ++m) t += bufA[m] * Wfc0[m * 128 + tid];
    bufB[tid] = fmaxf(t, 0.f);
  }
  __syncthreads();
  if (tid < 128) {
    float t = bfcm[tid];
    for (int m = 0; m < 128; ++m) t += bufB[m] * Wfcm[m * 128 + tid];
    bufA[tid] = fmaxf(t, 0.f);
  }
  __syncthreads();
  if (tid < 128) {
    float t = bfcm[128 + tid];
    for (int m = 0; m < 128; ++m) t += bufA[m] * Wfcm[128 * 128 + m * 128 + tid];
    bufB[tid] = fmaxf(t, 0.f);
  }
  __syncthreads();
  if (tid < 128) red[0][tid] = bufB[tid] * Wfcl[tid];
  __syncthreads();
  if (tid < 64) red[0][tid] += red[0][tid + 64];
  __syncthreads();
  if (tid == 0) {
    float r = 0.f;
#pragma unroll
    for (int j = 0; j < 64; ++j) r += red[0][j];
    out[b] = 1.f / (1.f + __expf(-(r + bfcl[0])));
  }
}

extern "C" void kernel_launch(void* const* d_in, const int* in_sizes, int n_in,
                              void* d_out, int out_size, void* d_ws, size_t ws_size,
                              hipStream_t stream) {
  (void)in_sizes; (void)n_in; (void)out_size;
  const float* x     = (const float*)d_in[0];
  const float* adj1  = (const float*)d_in[1];
  const float* adj2  = (const float*)d_in[2];
  const float* valid = (const float*)d_in[3];
  const float* Wemb  = (const float*)d_in[4];
  const float* Wh    = (const float*)d_in[5];
  const float* bh    = (const float*)d_in[6];
  const float* We    = (const float*)d_in[7];
  const float* Wb    = (const float*)d_in[8];
  const float* bb    = (const float*)d_in[9];
  const float* Wfc0  = (const float*)d_in[10];
  const float* bfc0  = (const float*)d_in[11];
  const float* Wfcm  = (const float*)d_in[12];
  const float* bfcm  = (const float*)d_in[13];
  const float* Wfcl  = (const float*)d_in[14];
  const float* bfcl  = (const float*)d_in[15];
  float* out = (float*)d_out;

  // branch strides (element counts)
  const size_t adjS  = (size_t)BB * NN * 128;   // u16
  const size_t cntS  = (size_t)BB * NN;         // u16
  const size_t betaS = (size_t)BB * NN * HH;    // f32
  const size_t zS    = (size_t)BB * NN * HH * DD; // bf16
  const size_t statsS = (size_t)BB * HH * NN;   // float2

  // ---- workspace (fp32-element offsets) ----
  float* w = (float*)d_ws;
  size_t off = 0;
  float* c    = w + off; off += (size_t)BB * NN * DD;
  float* beta = w + off; off += 2 * betaS;
  float2* stats = (float2*)(w + off); off += 2 * statsS * 2;
  float* hWb  = w + off; off += (size_t)BB * NN * HH;
  unsigned short* c_bf = (unsigned short*)(w + off); off += (size_t)BB * NN * DD / 2;
  unsigned short* h_bf = (unsigned short*)(w + off); off += (size_t)BB * NN * HH * DD / 2;
  unsigned short* g_bf = (unsigned short*)(w + off); off += (size_t)BB * NN * HH * DD / 2;
  unsigned short* zP0  = (unsigned short*)(w + off); off += 2 * zS / 2;
  unsigned short* zP1  = (unsigned short*)(w + off); off += 2 * zS / 2;
  unsigned short* WhT  = (unsigned short*)(w + off); off += (size_t)LL * 512 * 128 / 2;
  unsigned short* WeT  = (unsigned short*)(w + off); off += (size_t)LL * 128 * 128 / 2;
  unsigned int* maskT1 = (unsigned int*)(w + off); off += (size_t)BB * NN * 32;
  unsigned int* maskT2 = (unsigned int*)(w + off); off += (size_t)BB * NN * 32;
  unsigned short* cidxB = (unsigned short*)(w + off); off += 2 * adjS / 2;
  unsigned short* adjvB = (unsigned short*)(w + off); off += 2 * adjS / 2;
  unsigned short* cntB  = (unsigned short*)(w + off); off += (2 * cntS + 1) / 2;
  const size_t fixedF = off;
  const size_t eF = (size_t)HH * NN * NN / 2;  // per-batch fp16 E, floats
  const size_t aF = (size_t)HH * NN * 128;     // per-batch per-branch attP, floats
  const size_t wsF = ws_size / sizeof(float);

  int G = 8;
  while (G > 1 && fixedF + (size_t)G * (eF + 2 * aF) > wsF) G >>= 1;

  unsigned short* e = (unsigned short*)(w + fixedF);
  unsigned int* attP = (unsigned int*)(w + fixedF + (size_t)G * eF);
  const size_t attS = (size_t)G * HH * NN * 128; // u32 branch stride

  k_maskT<<<dim3(32, 32, BB), 256, 0, stream>>>(adj1, maskT1);
  k_maskT<<<dim3(32, 32, BB), 256, 0, stream>>>(adj2, maskT2);
  k_build<<<dim3(256, BB), 256, 0, stream>>>(adj1, cidxB, adjvB, cntB);
  k_build<<<dim3(256, BB), 256, 0, stream>>>(adj2, cidxB + adjS, adjvB + adjS, cntB + cntS);
  k_wtrans<<<dim3(4, 16, LL), 256, 0, stream>>>(Wh, WhT, 512);
  k_wtrans<<<dim3(4, 4, LL), 256, 0, stream>>>(We, WeT, 128);
  k_gemm_k128<<<dim3(128, 2), 256, 0, stream>>>(x, Wemb, c, c_bf, BB * NN, DD);

  for (int k = 0; k < LL; ++k) {
    k_gemm_nt<<<dim3(128, 8), 256, 0, stream>>>(
        c_bf, WhT + (size_t)k * 512 * 128, bh + (size_t)k * 512, h_bf, 512);
    k_gemm_nt<<<dim3(512, 2), 256, 0, stream>>>(
        h_bf, WeT + (size_t)k * 128 * 128, nullptr, g_bf, 128);
    k_hwb<<<BB * NN * HH / 4, 256, 0, stream>>>(h_bf, Wb + (size_t)k * 2 * DD, hWb);
    for (int b0 = 0; b0 < BB; b0 += G) {
      k_e_st<<<dim3(136, G * HH), 256, 0, stream>>>(g_bf, h_bf, e, b0);
      k_stats2<<<G * HH * NN, 128, 0, stream>>>(e, maskT1, maskT2, stats, statsS, b0);
      k_attw2<<<dim3(256, G * HH, 2), 256, 0, stream>>>(
          e, cidxB, adjvB, cntB, adjS, cntS, stats, statsS, attP, attS, b0);
      // az0 fused (relu + beta + mix) for both branches -> zP0
      k_az2<0><<<dim3(256, G * HH, 2), 256, 0, stream>>>(
          attP, attS, cntB, cntS, h_bf, 0, h_bf, hWb,
          Wb + (size_t)k * 2 * DD, bb + k, beta, betaS, zP0, zS, b0);
      unsigned short *cur = zP0, *nxt = zP1;
      for (int t = 2; t <= k + 1; ++t) {
        k_az2<1><<<dim3(256, G * HH, 2), 256, 0, stream>>>(
            attP, attS, cntB, cntS, cur, zS, h_bf, nullptr, nullptr, nullptr,
            beta, betaS, nxt, zS, b0);
        unsigned short* tm = cur; cur = nxt; nxt = tm;
      }
      const size_t oH = (size_t)b0 * NN * 512;
      const size_t oC = (size_t)b0 * NN * DD;
      k_headmean2<<<G * 512, 256, 0, stream>>>(
          cur + oH, cur + zS + oH, c + oC, c_bf + oC);
    }
  }
  k_final2<<<BB, 1024, 0, stream>>>(c, valid, Wfc0, bfc0, Wfcm, bfcm, Wfcl, bfcl, out);
}

// Round 9
// 1032.881 us; speedup vs baseline: 3.4894x; 1.1959x over previous
//
#include <hip/hip_runtime.h>
#include <hip/hip_bf16.h>

#define BB 8
#define NN 1024
#define DD 128
#define HH 4
#define LL 4

typedef __attribute__((ext_vector_type(8))) short bf16x8;
typedef __attribute__((ext_vector_type(4))) float f32x4;
typedef __attribute__((ext_vector_type(8))) unsigned short u16x8;

__device__ __forceinline__ unsigned short f2bf(float f) {
  union { float f; unsigned int u; } v; v.f = f;
  unsigned int u = v.u;
  return (unsigned short)((u + 0x7FFFu + ((u >> 16) & 1u)) >> 16);
}
__device__ __forceinline__ float bf2f(unsigned short s) {
  union { unsigned int u; float f; } v; v.u = ((unsigned int)s) << 16;
  return v.f;
}
__device__ __forceinline__ float ubf_lo(unsigned int u) {
  union { unsigned int u; float f; } v; v.u = u << 16;
  return v.f;
}
__device__ __forceinline__ float ubf_hi(unsigned int u) {
  union { unsigned int u; float f; } v; v.u = u & 0xFFFF0000u;
  return v.f;
}
__device__ __forceinline__ unsigned short f2h(float f) {
  union { _Float16 h; unsigned short u; } v; v.h = (_Float16)f;
  return v.u;
}
__device__ __forceinline__ float h2f(unsigned short u) {
  union { unsigned short u; _Float16 h; } v; v.u = u;
  return (float)v.h;
}

// ------- maskT bits: maskW[b][r][word w] bit t = (adj[b][p=32w+t][r] > 0) ------
__global__ __launch_bounds__(256) void k_maskT(const float* __restrict__ in,
                                               unsigned int* __restrict__ maskW) {
  __shared__ float t[32][33];
  int b = blockIdx.z;
  int x0 = blockIdx.x * 32, y0 = blockIdx.y * 32;
  int tx = threadIdx.x & 31, ty = threadIdx.x >> 5;
  const float* ib = in + (size_t)b * NN * NN;
#pragma unroll
  for (int j = 0; j < 32; j += 8)
    t[ty + j][tx] = ib[(size_t)(y0 + ty + j) * NN + x0 + tx];
  __syncthreads();
  const int half = (threadIdx.x >> 5) & 1;
#pragma unroll
  for (int j = 0; j < 32; j += 8) {
    bool nz = t[tx][ty + j] > 0.f;
    unsigned long long bl = __ballot(nz);
    unsigned int word = half ? (unsigned int)(bl >> 32) : (unsigned int)bl;
    if (tx == 0)
      maskW[((size_t)b * NN + x0 + ty + j) * 32 + (y0 >> 5)] = word;
  }
}

// ------- compact adj rows: colidx/adjv slots (stride 128) + cnt per row --------
__global__ __launch_bounds__(256) void k_build(const float* __restrict__ adj,
                                               unsigned short* __restrict__ colidx,
                                               unsigned short* __restrict__ adjv,
                                               unsigned short* __restrict__ cnt) {
  const int b = blockIdx.y;
  const int wv = threadIdx.x >> 6, lane = threadIdx.x & 63;
  const int p = blockIdx.x * 4 + wv;
  const float* arow = adj + ((size_t)b * NN + p) * NN;
  const size_t base = ((size_t)b * NN + p) * 128;
  int run = 0;
  const unsigned long long lml = (lane == 63) ? 0x7FFFFFFFFFFFFFFFull
                                              : ((1ull << lane) - 1ull);
#pragma unroll
  for (int it = 0; it < 16; ++it) {
    float v = arow[it * 64 + lane];
    bool nz = v > 0.f;
    unsigned long long m = __ballot(nz);
    int pre = __popcll(m & lml);
    int slot = run + pre;
    if (nz && slot < 128) {
      colidx[base + slot] = (unsigned short)(it * 64 + lane);
      adjv[base + slot] = f2bf(v);
    }
    run += __popcll(m);
  }
  if (lane == 0) cnt[(size_t)b * NN + p] = (unsigned short)(run > 128 ? 128 : run);
}

// ------- weight transpose: in [nm][128][Nn] fp32 -> out [nm][Nn][128] bf16 -----
__global__ __launch_bounds__(256) void k_wtrans(const float* __restrict__ in,
                                                unsigned short* __restrict__ out, int Nn) {
  __shared__ float t[32][33];
  int m = blockIdx.z;
  const float* ib = in + (size_t)m * 128 * Nn;
  unsigned short* ob = out + (size_t)m * Nn * 128;
  int k0 = blockIdx.x * 32, n0 = blockIdx.y * 32;
  int tx = threadIdx.x & 31, ty = threadIdx.x >> 5;
#pragma unroll
  for (int j = 0; j < 32; j += 8)
    t[ty + j][tx] = ib[(size_t)(k0 + ty + j) * Nn + n0 + tx];
  __syncthreads();
#pragma unroll
  for (int j = 0; j < 32; j += 8)
    ob[(size_t)(n0 + ty + j) * 128 + k0 + tx] = f2bf(t[tx][ty + j]);
}

// ------- SIMT K=128 GEMM (embed only): C = A[M,128] @ Bw[128,Nn]; fp32+bf16 ----
__global__ __launch_bounds__(256) void k_gemm_k128(const float* __restrict__ A,
                                                   const float* __restrict__ Bw,
                                                   float* __restrict__ C,
                                                   unsigned short* __restrict__ Cbf,
                                                   int M, int Nn) {
  __shared__ __align__(16) float As[32][68];
  __shared__ __align__(16) float Bs[32][68];
  const int tm = blockIdx.x * 64, tn = blockIdx.y * 64;
  const int tid = threadIdx.x;
  const int ty = tid >> 4, tx = tid & 15;
  float acc[4][4] = {};
  for (int kc = 0; kc < 128; kc += 32) {
#pragma unroll
    for (int e = 0; e < 8; ++e) {
      int fl = tid + e * 256;
      int r = fl >> 5, k = fl & 31;
      As[k][r] = A[(size_t)(tm + r) * 128 + kc + k];
    }
#pragma unroll
    for (int e = 0; e < 8; ++e) {
      int fl = tid + e * 256;
      int k = fl >> 6, n = fl & 63;
      Bs[k][n] = Bw[(size_t)(kc + k) * Nn + tn + n];
    }
    __syncthreads();
#pragma unroll
    for (int kk = 0; kk < 32; ++kk) {
      float a4[4], b4[4];
      *(float4*)a4 = *(const float4*)&As[kk][ty * 4];
      *(float4*)b4 = *(const float4*)&Bs[kk][tx * 4];
#pragma unroll
      for (int i = 0; i < 4; ++i)
#pragma unroll
        for (int j = 0; j < 4; ++j) acc[i][j] += a4[i] * b4[j];
    }
    __syncthreads();
  }
#pragma unroll
  for (int i = 0; i < 4; ++i) {
    size_t base = (size_t)(tm + ty * 4 + i) * Nn + tn + tx * 4;
    *(float4*)&C[base] = *(float4*)acc[i];
    uint2 pv;
    pv.x = (unsigned int)f2bf(acc[i][0]) | ((unsigned int)f2bf(acc[i][1]) << 16);
    pv.y = (unsigned int)f2bf(acc[i][2]) | ((unsigned int)f2bf(acc[i][3]) << 16);
    *(uint2*)&Cbf[base] = pv;
  }
}

// ------- MFMA NT GEMM, K=128: out[M,Nn](bf16) = A[M,128](bf16) @ Bt[Nn,128]^T --
__global__ __launch_bounds__(256) void k_gemm_nt(const unsigned short* __restrict__ A,
                                                 const unsigned short* __restrict__ Bt,
                                                 const float* __restrict__ bias,
                                                 unsigned short* __restrict__ outp,
                                                 int Nn) {
  const int m0 = blockIdx.x * 64, n0 = blockIdx.y * 64;
  const int tid = threadIdx.x;
  const int wave = tid >> 6, lane = tid & 63;
  const int l15 = lane & 15, kq = lane >> 4;
  __shared__ __align__(16) unsigned short O[64][72];
  const unsigned short* aP = A + (size_t)(m0 + wave * 16 + l15) * 128;
  f32x4 acc[4] = {};
#pragma unroll
  for (int kk = 0; kk < 4; ++kk) {
    bf16x8 aF = *(const bf16x8*)(aP + (kk * 4 + kq) * 8);
#pragma unroll
    for (int cb = 0; cb < 4; ++cb) {
      bf16x8 bF = *(const bf16x8*)(Bt + (size_t)(n0 + cb * 16 + l15) * 128 + (kk * 4 + kq) * 8);
      acc[cb] = __builtin_amdgcn_mfma_f32_16x16x32_bf16(aF, bF, acc[cb], 0, 0, 0);
    }
  }
#pragma unroll
  for (int cb = 0; cb < 4; ++cb) {
    float bv = bias ? bias[n0 + cb * 16 + l15] : 0.f;
#pragma unroll
    for (int rg = 0; rg < 4; ++rg)
      O[wave * 16 + kq * 4 + rg][cb * 16 + l15] = f2bf(acc[cb][rg] + bv);
  }
  __syncthreads();
#pragma unroll
  for (int it = 0; it < 2; ++it) {
    int row = (tid >> 3) + it * 32, ch = tid & 7;
    *(uint4*)&outp[(size_t)(m0 + row) * Nn + n0 + ch * 8] = *(uint4*)&O[row][ch * 8];
  }
}

// ------- E tile via MFMA -> fp16 [p][r]: triangular grid (136 live pairs) ------
__global__ __launch_bounds__(256) void k_e_st(const unsigned short* __restrict__ g,
                                              const unsigned short* __restrict__ h,
                                              unsigned short* __restrict__ e, int b0) {
  const int t0 = blockIdx.x; // 0..135 -> (tp <= tr)
  int tr = (int)((sqrtf(8.f * t0 + 1.f) - 1.f) * 0.5f);
  while ((tr + 1) * (tr + 2) / 2 <= t0) ++tr;
  while (tr * (tr + 1) / 2 > t0) --tr;
  const int tp = t0 - tr * (tr + 1) / 2;
  const int gi = blockIdx.y;
  const int b = b0 + (gi >> 2), i = gi & 3;
  const int p0 = tp * 64, r0 = tr * 64;
  const bool diag = (tp == tr);
  __shared__ __align__(16) char lds[32768];
  const int tid = threadIdx.x;
  const unsigned short* gb = g + (size_t)b * NN * 512 + i * 128;
  const unsigned short* hb = h + (size_t)b * NN * 512 + i * 128;
#pragma unroll
  for (int e2 = 0; e2 < 8; ++e2) {
    int fl = tid + e2 * 256;
    int t = fl >> 10, rem = fl & 1023;
    int row = rem >> 4, ch = rem & 15;
    const unsigned short* src = t ? hb : gb;
    uint4 v = *(const uint4*)(src + (size_t)(r0 + row) * 512 + ch * 8);
    *(uint4*)(lds + t * 16384 + row * 256 + ((ch ^ (row & 7)) * 16)) = v;
  }
  __syncthreads();
  const int wave = tid >> 6, lane = tid & 63;
  const int l15 = lane & 15, kq = lane >> 4;
  const unsigned short* aG = gb + (size_t)(p0 + wave * 16 + l15) * 512;
  const unsigned short* aH = hb + (size_t)(p0 + wave * 16 + l15) * 512;
  f32x4 acc[4] = {};
#pragma unroll
  for (int kk = 0; kk < 4; ++kk) {
    bf16x8 gA = *(const bf16x8*)(aG + (kk * 4 + kq) * 8);
    bf16x8 hA = *(const bf16x8*)(aH + (kk * 4 + kq) * 8);
#pragma unroll
    for (int cb = 0; cb < 4; ++cb) {
      int row = cb * 16 + l15;
      int chs = ((kk * 4 + kq) ^ (row & 7)) * 16;
      bf16x8 gB = *(const bf16x8*)(lds + row * 256 + chs);
      bf16x8 hB = *(const bf16x8*)(lds + 16384 + row * 256 + chs);
      acc[cb] = __builtin_amdgcn_mfma_f32_16x16x32_bf16(gA, hB, acc[cb], 0, 0, 0);
      acc[cb] = __builtin_amdgcn_mfma_f32_16x16x32_bf16(hA, gB, acc[cb], 0, 0, 0);
    }
  }
  __syncthreads();
  unsigned short* eN = (unsigned short*)lds;   // [64][72] fp16
  unsigned short* eT = eN + 64 * 72;
#pragma unroll
  for (int cb = 0; cb < 4; ++cb)
#pragma unroll
    for (int rg = 0; rg < 4; ++rg) {
      const int pl = wave * 16 + kq * 4 + rg, rl = cb * 16 + l15;
      const unsigned short v = f2h(acc[cb][rg]);
      eN[pl * 72 + rl] = v;
      if (!diag) eT[rl * 72 + pl] = v;
    }
  __syncthreads();
  unsigned short* eb = e + (size_t)gi * NN * NN;
#pragma unroll
  for (int it = 0; it < 2; ++it) {
    const int row = (tid >> 3) + it * 32, ch = tid & 7;
    *(uint4*)&eb[(size_t)(p0 + row) * NN + r0 + ch * 8] = *(uint4*)&eN[row * 72 + ch * 8];
    if (!diag)
      *(uint4*)&eb[(size_t)(r0 + row) * NN + p0 + ch * 8] = *(uint4*)&eT[row * 72 + ch * 8];
  }
}

// ------- both-branch stats from ONE E-row read: mx[r], inv[r] per branch -------
__global__ __launch_bounds__(128) void k_stats2(const unsigned short* __restrict__ e,
                                                const unsigned int* __restrict__ m1,
                                                const unsigned int* __restrict__ m2,
                                                float2* __restrict__ stats,
                                                size_t statsS, int b0) {
  const int col = blockIdx.x; // local gi*N + r
  const int r = col & (NN - 1);
  const int gi = col >> 10;
  const int b = b0 + (gi >> 2);
  const unsigned short* erow = e + (size_t)col * NN;
  const int tid = threadIdx.x;
  u16x8 ev = *(const u16x8*)(erow + tid * 8);
  float evf[8];
#pragma unroll
  for (int j = 0; j < 8; ++j) evf[j] = h2f((unsigned short)ev[j]);
  const size_t moff = ((size_t)b * NN + r) * 32 + (tid >> 2);
  const int sh = (tid & 3) * 8;
  unsigned int by1 = (m1[moff] >> sh) & 0xffu;
  unsigned int by2 = (m2[moff] >> sh) & 0xffu;
  float mx1 = 0.f, mx2 = 0.f; // masked entries contribute 0 -> max includes 0
#pragma unroll
  for (int j = 0; j < 8; ++j) {
    if ((by1 >> j) & 1u) mx1 = fmaxf(mx1, evf[j]);
    if ((by2 >> j) & 1u) mx2 = fmaxf(mx2, evf[j]);
  }
#pragma unroll
  for (int o = 32; o; o >>= 1) {
    mx1 = fmaxf(mx1, __shfl_xor(mx1, o));
    mx2 = fmaxf(mx2, __shfl_xor(mx2, o));
  }
  __shared__ float sm1[2], sm2[2], ss1[2], ss2[2];
  const int wv = tid >> 6, ln = tid & 63;
  if (ln == 0) { sm1[wv] = mx1; sm2[wv] = mx2; }
  __syncthreads();
  mx1 = fmaxf(sm1[0], sm1[1]);
  mx2 = fmaxf(sm2[0], sm2[1]);
  float ps1 = 0.f, ps2 = 0.f;
#pragma unroll
  for (int j = 0; j < 8; ++j) {
    float s1 = ((by1 >> j) & 1u) ? evf[j] : 0.f;
    float s2 = ((by2 >> j) & 1u) ? evf[j] : 0.f;
    ps1 += __expf(s1 - mx1);
    ps2 += __expf(s2 - mx2);
  }
#pragma unroll
  for (int o = 32; o; o >>= 1) {
    ps1 += __shfl_xor(ps1, o);
    ps2 += __shfl_xor(ps2, o);
  }
  if (ln == 0) { ss1[wv] = ps1; ss2[wv] = ps2; }
  __syncthreads();
  if (tid == 0) {
    const size_t gcol = (((size_t)gi + (size_t)b0 * HH) << 10) + r;
    stats[gcol] = make_float2(mx1, 1.f / (ss1[0] + ss1[1]));
    stats[statsS + gcol] = make_float2(mx2, 1.f / (ss2[0] + ss2[1]));
  }
}

// ------- sparse attw both branches -> att4[bl][p][head][128 slots] -------------
// slot word = (r<<16) | bf16(att); padded with 0 up to np4 (multiple of 4)
__global__ __launch_bounds__(256) void k_attw2(const unsigned short* __restrict__ e,
                                               const unsigned short* __restrict__ cidxB,
                                               const unsigned short* __restrict__ adjvB,
                                               const unsigned short* __restrict__ cntB,
                                               size_t adjS, size_t cntS,
                                               const float2* __restrict__ stats,
                                               size_t statsS,
                                               unsigned int* __restrict__ att4,
                                               size_t attS, int b0) {
  const int br = blockIdx.z;
  const int gi = blockIdx.y;          // local bl*H + head
  const int bl = gi >> 2, head = gi & 3;
  const int b = b0 + bl;
  const unsigned short* cidx = cidxB + (size_t)br * adjS;
  const unsigned short* adjv = adjvB + (size_t)br * adjS;
  const int wv = threadIdx.x >> 6, lane = threadIdx.x & 63;
  const int p = blockIdx.x * 4 + wv;
  const int n = cntB[(size_t)br * cntS + (size_t)b * NN + p];
  const int np4 = (n + 3) & ~3;
  const size_t cbase = ((size_t)b * NN + p) * 128;
  const unsigned short* erow = e + ((size_t)gi * NN + p) * NN;
  const float2* st = stats + (size_t)br * statsS + (((size_t)gi + (size_t)b0 * HH) << 10);
  unsigned int* ob = att4 + (size_t)br * attS + (((size_t)bl * NN + p) * 4 + head) * 128;
  for (int s = lane; s < np4; s += 64) {
    unsigned int o = 0;
    if (s < n) {
      int r = cidx[cbase + s];
      float2 mi = st[r];
      float val = __expf(h2f(erow[r]) - mi.x) * mi.y * bf2f(adjv[cbase + s]);
      o = ((unsigned int)r << 16) | (unsigned int)f2bf(val);
    }
    ob[s] = o;
  }
}

// ---- hWb[(b*N+n)*H+i] = sum_d h[...,d] * Wb_k[d] ------------------------------
__global__ __launch_bounds__(256) void k_hwb(const unsigned short* __restrict__ h,
                                             const float* __restrict__ Wbk,
                                             float* __restrict__ hWb) {
  const int wid = threadIdx.x >> 6, lane = threadIdx.x & 63;
  const int idx = blockIdx.x * 4 + wid;
  const unsigned short* hp = h + (size_t)idx * 128;
  float s = 0.f;
#pragma unroll
  for (int e = 0; e < 2; ++e) {
    int d = lane + e * 64;
    s += bf2f(hp[d]) * Wbk[d];
  }
#pragma unroll
  for (int o = 32; o; o >>= 1) s += __shfl_xor(s, o);
  if (lane == 0) hWb[idx] = s;
}

// ---- sparse az, all 4 heads per wave: lane owns 8 elems of the 512-wide row ---
// MODE 0: az0 — beta in-kernel, mix -> z.  MODE 1: hop — read beta, mix -> z.
template <int MODE>
__global__ __launch_bounds__(256) void k_az4(const unsigned int* __restrict__ att4,
                                             size_t attS,
                                             const unsigned short* __restrict__ cntB,
                                             size_t cntS,
                                             const unsigned short* __restrict__ zin,
                                             size_t zinS,
                                             const unsigned short* __restrict__ h,
                                             const float* __restrict__ hWb,
                                             const float* __restrict__ Wbk,
                                             const float* __restrict__ bbk,
                                             float* __restrict__ betaB, size_t betaS,
                                             unsigned short* __restrict__ outB,
                                             size_t outS, int b0) {
  const int br = blockIdx.z;
  const int bl = blockIdx.y;
  const int b = b0 + bl;
  const int wv = threadIdx.x >> 6, lane = threadIdx.x & 63;
  const int p = blockIdx.x * 4 + wv;
  const int head = lane >> 4;
  const int n = cntB[(size_t)br * cntS + (size_t)b * NN + p];
  const int np4 = (n + 3) & ~3;
  const unsigned int* ap =
      att4 + (size_t)br * attS + (((size_t)bl * NN + p) * 4 + head) * 128;
  const unsigned short* zbase = zin + (size_t)br * zinS + (size_t)b * NN * 512;
  const unsigned laneoff = (unsigned)lane * 8u;
  float a[8] = {};
  for (int s = 0; s < np4; s += 4) {
    uint4 aw = *(const uint4*)(ap + s);
    unsigned i0 = ((aw.x >> 7) & 0xFFFFFE00u) + laneoff;
    unsigned i1 = ((aw.y >> 7) & 0xFFFFFE00u) + laneoff;
    unsigned i2 = ((aw.z >> 7) & 0xFFFFFE00u) + laneoff;
    unsigned i3 = ((aw.w >> 7) & 0xFFFFFE00u) + laneoff;
    uint4 z0 = *(const uint4*)(zbase + i0);
    uint4 z1 = *(const uint4*)(zbase + i1);
    uint4 z2 = *(const uint4*)(zbase + i2);
    uint4 z3 = *(const uint4*)(zbase + i3);
    union { unsigned int u; float f; } c0, c1, c2, c3;
    c0.u = aw.x << 16; c1.u = aw.y << 16; c2.u = aw.z << 16; c3.u = aw.w << 16;
#define ACC8(zq, vv)                                            \
    a[0] += vv * ubf_lo(zq.x); a[1] += vv * ubf_hi(zq.x);       \
    a[2] += vv * ubf_lo(zq.y); a[3] += vv * ubf_hi(zq.y);       \
    a[4] += vv * ubf_lo(zq.z); a[5] += vv * ubf_hi(zq.z);       \
    a[6] += vv * ubf_lo(zq.w); a[7] += vv * ubf_hi(zq.w);
    ACC8(z0, c0.f) ACC8(z1, c1.f) ACC8(z2, c2.f) ACC8(z3, c3.f)
#undef ACC8
  }
#pragma unroll
  for (int j = 0; j < 8; ++j) a[j] = fmaxf(a[j], 0.f);
  const size_t gidx = ((size_t)b * NN + p) * HH + head;
  float bt;
  if (MODE == 0) {
    const float* wb2 = Wbk + 128 + (lane & 15) * 8;
    float part = 0.f;
#pragma unroll
    for (int j = 0; j < 8; ++j) part += a[j] * wb2[j];
    part += __shfl_xor(part, 1);
    part += __shfl_xor(part, 2);
    part += __shfl_xor(part, 4);
    part += __shfl_xor(part, 8); // full 128-dim sum within the 16-lane head group
    bt = 1.f / (1.f + __expf(-(hWb[gidx] + part + bbk[0])));
    if ((lane & 15) == 0) betaB[(size_t)br * betaS + gidx] = bt;
  } else {
    bt = betaB[(size_t)br * betaS + gidx];
  }
  const float om = 1.f - bt;
  const size_t obase = ((size_t)b * NN + p) * 512 + laneoff;
  uint4 hv = *(const uint4*)(h + obase);
  uint4 zo;
  zo.x = (unsigned int)f2bf(bt * ubf_lo(hv.x) + om * a[0]) |
         ((unsigned int)f2bf(bt * ubf_hi(hv.x) + om * a[1]) << 16);
  zo.y = (unsigned int)f2bf(bt * ubf_lo(hv.y) + om * a[2]) |
         ((unsigned int)f2bf(bt * ubf_hi(hv.y) + om * a[3]) << 16);
  zo.z = (unsigned int)f2bf(bt * ubf_lo(hv.z) + om * a[4]) |
         ((unsigned int)f2bf(bt * ubf_hi(hv.z) + om * a[5]) << 16);
  zo.w = (unsigned int)f2bf(bt * ubf_lo(hv.w) + om * a[6]) |
         ((unsigned int)f2bf(bt * ubf_hi(hv.w) + om * a[7]) << 16);
  *(uint4*)(outB + (size_t)br * outS + obase) = zo;
}

// ---- out[n,d] = mean_i z2[n,i,d] - mean_i z1[n,i,d]; c fp32 + bf16 ------------
__global__ __launch_bounds__(256) void k_headmean2(const unsigned short* __restrict__ z1,
                                                   const unsigned short* __restrict__ z2,
                                                   float* __restrict__ outp,
                                                   unsigned short* __restrict__ outbf) {
  const int idx = blockIdx.x * 256 + threadIdx.x;
  const int d = idx & 127, bn = idx >> 7;
  const size_t base = (size_t)bn * 512 + d;
  float v1 = bf2f(z1[base]) + bf2f(z1[base + 128]) + bf2f(z1[base + 256]) + bf2f(z1[base + 384]);
  float v2 = bf2f(z2[base]) + bf2f(z2[base + 128]) + bf2f(z2[base + 256]) + bf2f(z2[base + 384]);
  float v = 0.25f * (v2 - v1);
  outp[idx] = v;
  outbf[idx] = f2bf(v);
}

// ---------------- node mean (parallel) + MLP head ------------------------------
__global__ __launch_bounds__(1024) void k_final2(const float* __restrict__ c,
                                                 const float* __restrict__ valid,
                                                 const float* __restrict__ Wfc0,
                                                 const float* __restrict__ bfc0,
                                                 const float* __restrict__ Wfcm,
                                                 const float* __restrict__ bfcm,
                                                 const float* __restrict__ Wfcl,
                                                 const float* __restrict__ bfcl,
                                                 float* __restrict__ out) {
  const int b = blockIdx.x, tid = threadIdx.x;
  const int ns = tid >> 7, d = tid & 127;
  __shared__ float red[8][128];
  __shared__ float vsh[8];
  __shared__ float bufA[128], bufB[128];
  float s = 0.f, vs = 0.f;
  const float* cb = c + ((size_t)b * NN + ns * 128) * 128 + d;
  const float* vb = valid + (size_t)b * NN + ns * 128;
  for (int n2 = 0; n2 < 128; ++n2) {
    float vv = vb[n2];
    s += cb[(size_t)n2 * 128] * vv;
    vs += vv;
  }
  red[ns][d] = s;
  if (d == 0) vsh[ns] = vs;
  __syncthreads();
  if (tid < 128) {
    float m = 0.f, vt = 0.f;
#pragma unroll
    for (int j = 0; j < 8; ++j) { m += red[j][tid]; vt += vsh[j]; }
    bufA[tid] = m / vt;
  }
  __syncthreads();
  if (tid < 128) {
    float t = bfc0[tid];
    for (int m = 0; m < 128; ++m) t += bufA[m] * Wfc0[m * 128 + tid];
    bufB[tid] = fmaxf(t, 0.f);
  }
  __syncthreads();
  if (tid < 128) {
    float t = bfcm[tid];
    for (int m = 0; m < 128; ++m) t += bufB[m] * Wfcm[m * 128 + tid];
    bufA[tid] = fmaxf(t, 0.f);
  }
  __syncthreads();
  if (tid < 128) {
    float t = bfcm[128 + tid];
    for (int m = 0; m < 128; ++m) t += bufA[m] * Wfcm[128 * 128 + m * 128 + tid];
    bufB[tid] = fmaxf(t, 0.f);
  }
  __syncthreads();
  if (tid < 128) red[0][tid] = bufB[tid] * Wfcl[tid];
  __syncthreads();
  if (tid < 64) red[0][tid] += red[0][tid + 64];
  __syncthreads();
  if (tid == 0) {
    float r = 0.f;
#pragma unroll
    for (int j = 0; j < 64; ++j) r += red[0][j];
    out[b] = 1.f / (1.f + __expf(-(r + bfcl[0])));
  }
}

extern "C" void kernel_launch(void* const* d_in, const int* in_sizes, int n_in,
                              void* d_out, int out_size, void* d_ws, size_t ws_size,
                              hipStream_t stream) {
  (void)in_sizes; (void)n_in; (void)out_size;
  const float* x     = (const float*)d_in[0];
  const float* adj1  = (const float*)d_in[1];
  const float* adj2  = (const float*)d_in[2];
  const float* valid = (const float*)d_in[3];
  const float* Wemb  = (const float*)d_in[4];
  const float* Wh    = (const float*)d_in[5];
  const float* bh    = (const float*)d_in[6];
  const float* We    = (const float*)d_in[7];
  const float* Wb    = (const float*)d_in[8];
  const float* bb    = (const float*)d_in[9];
  const float* Wfc0  = (const float*)d_in[10];
  const float* bfc0  = (const float*)d_in[11];
  const float* Wfcm  = (const float*)d_in[12];
  const float* bfcm  = (const float*)d_in[13];
  const float* Wfcl  = (const float*)d_in[14];
  const float* bfcl  = (const float*)d_in[15];
  float* out = (float*)d_out;

  // branch strides (element counts)
  const size_t adjS  = (size_t)BB * NN * 128;     // u16
  const size_t cntS  = (size_t)BB * NN;           // u16
  const size_t betaS = (size_t)BB * NN * HH;      // f32
  const size_t zS    = (size_t)BB * NN * HH * DD; // bf16
  const size_t statsS = (size_t)BB * HH * NN;     // float2

  // ---- workspace (fp32-element offsets) ----
  float* w = (float*)d_ws;
  size_t off = 0;
  float* c    = w + off; off += (size_t)BB * NN * DD;
  float* beta = w + off; off += 2 * betaS;
  float2* stats = (float2*)(w + off); off += 2 * statsS * 2;
  float* hWb  = w + off; off += (size_t)BB * NN * HH;
  unsigned short* c_bf = (unsigned short*)(w + off); off += (size_t)BB * NN * DD / 2;
  unsigned short* h_bf = (unsigned short*)(w + off); off += (size_t)BB * NN * HH * DD / 2;
  unsigned short* g_bf = (unsigned short*)(w + off); off += (size_t)BB * NN * HH * DD / 2;
  unsigned short* zP0  = (unsigned short*)(w + off); off += 2 * zS / 2;
  unsigned short* zP1  = (unsigned short*)(w + off); off += 2 * zS / 2;
  unsigned short* WhT  = (unsigned short*)(w + off); off += (size_t)LL * 512 * 128 / 2;
  unsigned short* WeT  = (unsigned short*)(w + off); off += (size_t)LL * 128 * 128 / 2;
  unsigned int* maskT1 = (unsigned int*)(w + off); off += (size_t)BB * NN * 32;
  unsigned int* maskT2 = (unsigned int*)(w + off); off += (size_t)BB * NN * 32;
  unsigned short* cidxB = (unsigned short*)(w + off); off += 2 * adjS / 2;
  unsigned short* adjvB = (unsigned short*)(w + off); off += 2 * adjS / 2;
  unsigned short* cntB  = (unsigned short*)(w + off); off += (2 * cntS + 1) / 2;
  const size_t fixedF = off;
  const size_t eF = (size_t)HH * NN * NN / 2;  // per-batch fp16 E, floats
  const size_t aF = (size_t)HH * NN * 128;     // per-batch per-branch att4, floats
  const size_t wsF = ws_size / sizeof(float);

  int G = 8;
  while (G > 1 && fixedF + (size_t)G * (eF + 2 * aF) > wsF) G >>= 1;

  unsigned short* e = (unsigned short*)(w + fixedF);
  unsigned int* att4 = (unsigned int*)(w + fixedF + (size_t)G * eF);
  const size_t attS = (size_t)G * NN * 512; // u32 branch stride ([bl][p][head][128])

  k_maskT<<<dim3(32, 32, BB), 256, 0, stream>>>(adj1, maskT1);
  k_maskT<<<dim3(32, 32, BB), 256, 0, stream>>>(adj2, maskT2);
  k_build<<<dim3(256, BB), 256, 0, stream>>>(adj1, cidxB, adjvB, cntB);
  k_build<<<dim3(256, BB), 256, 0, stream>>>(adj2, cidxB + adjS, adjvB + adjS, cntB + cntS);
  k_wtrans<<<dim3(4, 16, LL), 256, 0, stream>>>(Wh, WhT, 512);
  k_wtrans<<<dim3(4, 4, LL), 256, 0, stream>>>(We, WeT, 128);
  k_gemm_k128<<<dim3(128, 2), 256, 0, stream>>>(x, Wemb, c, c_bf, BB * NN, DD);

  for (int k = 0; k < LL; ++k) {
    k_gemm_nt<<<dim3(128, 8), 256, 0, stream>>>(
        c_bf, WhT + (size_t)k * 512 * 128, bh + (size_t)k * 512, h_bf, 512);
    k_gemm_nt<<<dim3(512, 2), 256, 0, stream>>>(
        h_bf, WeT + (size_t)k * 128 * 128, nullptr, g_bf, 128);
    k_hwb<<<BB * NN * HH / 4, 256, 0, stream>>>(h_bf, Wb + (size_t)k * 2 * DD, hWb);
    for (int b0 = 0; b0 < BB; b0 += G) {
      k_e_st<<<dim3(136, G * HH), 256, 0, stream>>>(g_bf, h_bf, e, b0);
      k_stats2<<<G * HH * NN, 128, 0, stream>>>(e, maskT1, maskT2, stats, statsS, b0);
      k_attw2<<<dim3(256, G * HH, 2), 256, 0, stream>>>(
          e, cidxB, adjvB, cntB, adjS, cntS, stats, statsS, att4, attS, b0);
      // az0 fused (relu + beta + mix) for both branches -> zP0
      k_az4<0><<<dim3(256, G, 2), 256, 0, stream>>>(
          att4, attS, cntB, cntS, h_bf, 0, h_bf, hWb,
          Wb + (size_t)k * 2 * DD, bb + k, beta, betaS, zP0, zS, b0);
      unsigned short *cur = zP0, *nxt = zP1;
      for (int t = 2; t <= k + 1; ++t) {
        k_az4<1><<<dim3(256, G, 2), 256, 0, stream>>>(
            att4, attS, cntB, cntS, cur, zS, h_bf, nullptr, nullptr, nullptr,
            beta, betaS, nxt, zS, b0);
        unsigned short* tm = cur; cur = nxt; nxt = tm;
      }
      const size_t oH = (size_t)b0 * NN * 512;
      const size_t oC = (size_t)b0 * NN * DD;
      k_headmean2<<<G * 512, 256, 0, stream>>>(
          cur + oH, cur + zS + oH, c + oC, c_bf + oC);
    }
  }
  k_final2<<<BB, 1024, 0, stream>>>(c, valid, Wfc0, bfc0, Wfcm, bfcm, Wfcl, bfcl, out);
}